// Round 1
// 133.692 us; speedup vs baseline: 1.1050x; 1.1050x over previous
//
#include <hip/hip_runtime.h>
#include <hip/hip_bf16.h>

// B=8, C_IN=C_OUT=64, H=W=64, K=3, N=9, PAD=1; padded coords in [0,65]
// f32 in, f32 out.
// R15 = R14 + transposed-x gather path:
//  - k0_prep additionally transposes x[b][c][h][w] -> xT[b][h][w][c] (workspace)
//  - Phase D samples via ONE float4 per corner (4 channels contiguous) instead
//    of 4 scalar loads: 72 instead of 288 VMEM ops/thread, full-line use.
//  - K-dim reordered n-major (k = n*64 + c): xo LDS writes become ds_write_b64,
//    wfrag prep reordered to match, dot loop uses ks = ksl*2 + s.
//  - XCD swizzle bh = (bid&7)*64 + (bid>>3): each XCD owns one batch b ->
//    x[b]+xT[b] = 2MB resident in its 4MB L2 -> gathers are L2-local.
//  - float4 output stores.

typedef unsigned int u32;
typedef unsigned short u16;
typedef short s8v __attribute__((ext_vector_type(8)));     // 8 bf16 (4 VGPR)
typedef short s4v __attribute__((ext_vector_type(4)));     // 4 bf16 (2 VGPR)
typedef float f4v __attribute__((ext_vector_type(4)));     // MFMA acc / float4

__device__ __forceinline__ u16 f2bf(float f) {
  u32 u = __builtin_bit_cast(u32, f);
  u32 r = (u + 0x7FFFu + ((u >> 16) & 1u)) >> 16;   // RNE, finite inputs
  return (u16)r;
}

// ---------- k0: weight prep + x transpose ----------
// wfrag[nt][ks][lane][j] bf16: B-fragment for mfma_16x16x32_bf16
//   co = nt*16 + (lane&15);  chunk ks: n = ks>>1, s = ks&1,
//   c = s*32 + (lane>>4)*8 + j    (K order: k = n*64 + c)
// woff_r[c][o][12] f32 (9 used, pad 12 for float4 alignment)
// xT[b][h][w][c] f32
__global__ __launch_bounds__(256) void k0_prep(
    const float* __restrict__ x,      // [8][64][64][64]
    const float* __restrict__ wconv,  // [64][576]  (576 = c*9+n)
    const float* __restrict__ woff,   // [18][64][9]
    u16* __restrict__ wfrag,          // 4*18*64*8 = 36864 bf16
    float* __restrict__ woff_r,       // 64*216 f32
    float* __restrict__ xT) {         // [8][64][64][64] transposed
  __shared__ float tile[64][65];
  int bid = blockIdx.x;               // grid 512
  int t = threadIdx.x;
  int tid = bid * 256 + t;

  if (tid < 4608) {
    int nt = tid / 1152, ks = (tid / 64) % 18, lane = tid & 63;
    int co = nt * 16 + (lane & 15);
    int n = ks >> 1, s = ks & 1;
    int cl = (lane >> 4) << 3;
    u16* dst = wfrag + tid * 8;
    #pragma unroll
    for (int j = 0; j < 8; ++j) {
      int c = s * 32 + cl + j;
      dst[j] = f2bf(wconv[co * 576 + c * 9 + n]);
    }
  }
  if (tid < 10368) {
    int o = tid / 576, c = (tid / 9) % 64, k = tid % 9;
    woff_r[c * 216 + o * 12 + k] = woff[tid];
  }

  // transpose one (b,h) row-plane: 64 c x 64 w -> 64 w x 64 c
  int bh = ((bid & 7) << 6) | (bid >> 3);   // same XCD mapping as deform_one
  const float* xb = x + (bh >> 6) * 262144 + (bh & 63) * 64;
  int w = t & 63, cr = t >> 6;
  #pragma unroll
  for (int i = 0; i < 16; ++i) {
    int c = cr * 16 + i;
    tile[c][w] = xb[c * 4096 + w];          // coalesced read
  }
  __syncthreads();
  float* dstT = xT + bh * 4096;
  int c2 = t & 63, wr = t >> 6;
  #pragma unroll
  for (int i = 0; i < 16; ++i) {
    int w2 = wr * 16 + i;
    dstT[w2 * 64 + c2] = tile[c2][w2];      // coalesced write, stride-65 LDS read
  }
}

// ---------- fused main: one block per (b,h), 512 blocks x 512 threads ----------
__global__ __launch_bounds__(512, 4) void deform_one(
    const float* __restrict__ x,        // [8][64][64][64]  (Phase B only)
    const float* __restrict__ woff_r,   // [64][18][12] f32
    const float* __restrict__ boff,     // [18]
    const u16*  __restrict__ wfrag,     // B-fragments bf16
    const float* __restrict__ xT,       // [8][64][64][64] transposed
    float* __restrict__ out) {          // [8][64][64][64]
  __shared__ __align__(16) u16 xos[64 * 296];  // 37888B: Phase-B partials (f32) then xo bf16 [w][296]
  __shared__ f4v   gw[576];       // 9216B [n][w] validity-folded bilinear weights
  __shared__ u32   qq[576];       // 2304B [n][w] packed 0-based corner coords
  __shared__ float offs_s[1152];  // 4608B [o][w]      total 54016B

  int bid = blockIdx.x;
  int bh = ((bid & 7) << 6) | (bid >> 3);   // XCD k -> batch k
  int b = bh >> 6, h = bh & 63;
  int t = threadIdx.x;
  int wlane = t & 63;
  int wv = __builtin_amdgcn_readfirstlane(t >> 6);   // 0..7
  const float* xb = x + b * 262144;

  // ---- Phase B: offset conv, wave wv owns channels [8wv, 8wv+8), x from global ----
  {
    int w = wlane;
    bool lf = w > 0, rt = w < 63;
    float acc[18];
    #pragma unroll
    for (int o = 0; o < 18; ++o) acc[o] = 0.f;

    for (int cl = 0; cl < 8; ++cl) {
      int c = wv * 8 + cl;
      const float* xc = xb + c * 4096;
      float v[9];
      #pragma unroll
      for (int kh = 0; kh < 3; ++kh) {
        int hh = h + kh - 1;
        bool vr = (hh >= 0 && hh < 64);
        const float* row = xc + hh * 64;
        v[kh * 3 + 0] = (vr && lf) ? row[w - 1] : 0.f;
        v[kh * 3 + 1] = vr         ? row[w]     : 0.f;
        v[kh * 3 + 2] = (vr && rt) ? row[w + 1] : 0.f;
      }
      const float4* wc4 = (const float4*)(woff_r + c * 216);  // wave-uniform -> s_load
      #pragma unroll
      for (int o = 0; o < 18; ++o) {
        float4 wa  = wc4[o * 3 + 0];
        float4 wb  = wc4[o * 3 + 1];
        float4 wcv = wc4[o * 3 + 2];
        acc[o] += v[0]*wa.x + v[1]*wa.y + v[2]*wa.z + v[3]*wa.w
                + v[4]*wb.x + v[5]*wb.y + v[6]*wb.z + v[7]*wb.w
                + v[8]*wcv.x;
      }
    }

    // two-step cross-wave reduction in the xos region (aliased as f32)
    float* part = (float*)xos;                 // 4 regions x 1152 f32 = 18432B
    if (wv >= 4) {
      float* reg = part + (wv - 4) * 1152;
      #pragma unroll
      for (int o = 0; o < 18; ++o)
        reg[o * 64 + w] = acc[o];
    }
    __syncthreads();
    if (wv < 4) {
      float* reg = part + wv * 1152;
      #pragma unroll
      for (int o = 0; o < 18; ++o)
        reg[o * 64 + w] += acc[o];
    }
    __syncthreads();
    for (int i = t; i < 1152; i += 512) {
      int o = i >> 6;
      float s = boff[o] + part[i] + part[1152 + i] + part[2304 + i] + part[3456 + i];
      offs_s[i] = s;
    }
  }
  __syncthreads();

  // ---- Phase C: corners + bilinear weights, validity folded ----
  for (int p = t; p < 576; p += 512) {
    int n  = p >> 6;       // p = n*64 + w
    int ww = p & 63;
    float ox = offs_s[n * 64 + ww];
    float oy = offs_s[(9 + n) * 64 + ww];
    float px = (float)(h + (n / 3)) + ox;   // (h+1)+(n/3-1)+ox
    float py = (float)(ww + (n % 3)) + oy;
    float fx = floorf(px), fy = floorf(py);
    float pxc  = fminf(fmaxf(px, 0.f), 65.f);
    float pyc  = fminf(fmaxf(py, 0.f), 65.f);
    float fltx = fminf(fmaxf(fx, 0.f), 65.f);
    float flty = fminf(fmaxf(fy, 0.f), 65.f);
    float frbx = fminf(fmaxf(fx + 1.f, 0.f), 65.f);
    float frby = fminf(fmaxf(fy + 1.f, 0.f), 65.f);
    float ax = 1.f + fltx - pxc, bx = 1.f - frbx + pxc;
    float ay = 1.f + flty - pyc, by = 1.f - frby + pyc;
    float glt = ax * ay, grb = bx * by, glb = ax * by, grt = bx * ay;

    int ilt = (int)fltx, jlt = (int)flty, irb = (int)frbx, jrb = (int)frby;
    bool bi0 = (ilt >= 1 && ilt <= 64), bj0 = (jlt >= 1 && jlt <= 64);
    bool bi1 = (irb >= 1 && irb <= 64), bj1 = (jrb >= 1 && jrb <= 64);
    u32 i0 = bi0 ? (u32)(ilt - 1) : 0u;
    u32 j0 = bj0 ? (u32)(jlt - 1) : 0u;
    u32 i1 = bi1 ? (u32)(irb - 1) : 0u;
    u32 j1 = bj1 ? (u32)(jrb - 1) : 0u;
    f4v gv;
    gv[0] = (bi0 && bj0) ? glt : 0.f;
    gv[1] = (bi1 && bj1) ? grb : 0.f;
    gv[2] = (bi0 && bj1) ? glb : 0.f;
    gv[3] = (bi1 && bj0) ? grt : 0.f;
    gw[p] = gv;
    qq[p] = i0 | (j0 << 8) | (i1 << 16) | (j1 << 24);
  }
  __syncthreads();

  // ---- Phase D: 2 slices of 32 c: sample via xT float4 -> xo bf16, MFMA dot ----
  int m0 = wv & 3;                      // w-tile
  int n0 = (wv >> 2) * 2;               // co-tiles n0, n0+1
  int aoff = (m0 * 16 + (wlane & 15)) * 296 + ((wlane >> 4) << 3);
  const s8v* Wf = (const s8v*)wfrag;    // [(nt*18+ks)*64 + lane]
  f4v acc0 = {0.f, 0.f, 0.f, 0.f}, acc1 = {0.f, 0.f, 0.f, 0.f};
  const float* xTb = xT + b * 262144;

  for (int s = 0; s < 2; ++s) {
    // sample: thread covers channels cb..cb+3 (contiguous in xT), lane's w, all 9 n
    int cb = s * 32 + wv * 4;
    const float* xq = xTb + cb;
    #pragma unroll
    for (int n = 0; n < 9; ++n) {
      f4v g  = gw[n * 64 + wlane];
      u32 q  = qq[n * 64 + wlane];
      int i0 = (int)(q & 255u) << 12;          // *4096 floats (row stride 64*64)
      int j0 = (int)((q >> 8) & 255u) << 6;    // *64 floats
      int i1 = (int)((q >> 16) & 255u) << 12;
      int j1 = (int)(q >> 24) << 6;
      f4v lt = *(const f4v*)(xq + i0 + j0);
      f4v rb = *(const f4v*)(xq + i1 + j1);
      f4v lb = *(const f4v*)(xq + i0 + j1);
      f4v rt = *(const f4v*)(xq + i1 + j0);
      f4v v  = g[0]*lt + g[1]*rb + g[2]*lb + g[3]*rt;
      s4v pk;
      pk[0] = (short)f2bf(v[0]);
      pk[1] = (short)f2bf(v[1]);
      pk[2] = (short)f2bf(v[2]);
      pk[3] = (short)f2bf(v[3]);
      // xo layout: [w][n*32 + cl] (K order n-major), 8B-aligned b64 write
      *(s4v*)(xos + wlane * 296 + n * 32 + wv * 4) = pk;
    }
    __syncthreads();

    // dot: 9 K-chunks of 32 (chunk ksl = n); A from LDS (b128), B from global
    #pragma unroll
    for (int ksl = 0; ksl < 9; ++ksl) {
      s8v a = *(const s8v*)(xos + aoff + ksl * 32);
      int ks = ksl * 2 + s;                 // global chunk: n = ksl, half = s
      s8v b0 = Wf[(n0 * 18 + ks) * 64 + wlane];
      s8v b1 = Wf[((n0 + 1) * 18 + ks) * 64 + wlane];
      acc0 = __builtin_amdgcn_mfma_f32_16x16x32_bf16(a, b0, acc0, 0, 0, 0);
      acc1 = __builtin_amdgcn_mfma_f32_16x16x32_bf16(a, b1, acc1, 0, 0, 0);
    }
    __syncthreads();
  }

  // ---- store: D layout col=lane&15 (co-local), row=quad*4+reg (w-local) ----
  float* ob = out + b * 262144 + h * 64;
  int quad = wlane >> 4;
  int w_b  = m0 * 16 + quad * 4;
  int co0  = n0 * 16 + (wlane & 15);
  int co1  = co0 + 16;
  *(f4v*)(ob + co0 * 4096 + w_b) = acc0;   // acc[r] -> w_b + r, 16B aligned
  *(f4v*)(ob + co1 * 4096 + w_b) = acc1;
}

extern "C" void kernel_launch(void* const* d_in, const int* in_sizes, int n_in,
                              void* d_out, int out_size, void* d_ws, size_t ws_size,
                              hipStream_t stream) {
  const float *x = nullptr, *woff = nullptr, *boff = nullptr, *wconv = nullptr;
  for (int i = 0; i < n_in; ++i) {
    switch (in_sizes[i]) {
      case 2097152: x     = (const float*)d_in[i]; break;
      case 10368:   woff  = (const float*)d_in[i]; break;
      case 18:      boff  = (const float*)d_in[i]; break;
      case 36864:   wconv = (const float*)d_in[i]; break;
      default: break;
    }
  }
  if (!x)     x     = (const float*)d_in[0];
  if (!woff)  woff  = (const float*)d_in[1];
  if (!boff)  boff  = (const float*)d_in[2];
  if (!wconv) wconv = (const float*)d_in[3];
  float* out = (float*)d_out;

  u16*   wfrag  = (u16*)d_ws;                        // 73728 B
  float* woff_r = (float*)((char*)d_ws + 73728);     // 55296 B (ends 129024)
  float* xT     = (float*)((char*)d_ws + 131072);    // 8388608 B transposed x
  // total workspace use: 131072 + 8388608 = 8519680 B

  k0_prep<<<512, 256, 0, stream>>>(x, wconv, woff, wfrag, woff_r, xT);
  deform_one<<<512, 512, 0, stream>>>(x, woff_r, boff, wfrag, xT, out);
}

// Round 3
// 115.292 us; speedup vs baseline: 1.2814x; 1.1596x over previous
//
#include <hip/hip_runtime.h>
#include <hip/hip_bf16.h>

// B=8, C_IN=C_OUT=64, H=W=64, K=3, N=9, PAD=1; padded coords in [0,65]
// f32 in, f32 out.
// R17 = R16 with the xos row-stride bug fixed: k2 holds the FULL K=576 per
// w-row (no K-slicing), so the row stride must be >=576 u16. R16 kept R15's
// 296 -> rows overlapped -> absmax 4.16. Now XOS_STRIDE=592 u16 (1184B,
// multiple of 16B for aligned ds_read_b128; s4v writes 8B-aligned).
// LDS/block: 16*592*2 + 2304 + 576 = 21824B -> 7 blocks/CU (28 waves, 87.5%).
//  - k0_prep: wfrag n-major, woff_r, x -> xT transpose
//  - k1_offsets: offset conv at 512x512, writes offsets (incl bias) to ws
//  - k2_sample: 2048 blocks x 256 threads, block=(b,h,wq of 16 w), c-major
//    gathers: 16 consecutive lanes read 16 consecutive float4s of one corner
//    row -> contiguous 256B segments per load instruction.

typedef unsigned int u32;
typedef unsigned short u16;
typedef short s8v __attribute__((ext_vector_type(8)));     // 8 bf16 (4 VGPR)
typedef short s4v __attribute__((ext_vector_type(4)));     // 4 bf16 (2 VGPR)
typedef float f4v __attribute__((ext_vector_type(4)));     // MFMA acc / float4

#define XOS_STRIDE 592   // u16 per w-row (>=576, multiple of 8)

__device__ __forceinline__ u16 f2bf(float f) {
  u32 u = __builtin_bit_cast(u32, f);
  u32 r = (u + 0x7FFFu + ((u >> 16) & 1u)) >> 16;   // RNE, finite inputs
  return (u16)r;
}

// ---------- k0: weight prep + x transpose ----------
// wfrag[nt][ks][lane][j] bf16: B-fragment for mfma_16x16x32_bf16
//   co = nt*16 + (lane&15);  chunk ks: n = ks>>1, s = ks&1,
//   c = s*32 + (lane>>4)*8 + j    (K order: k = n*64 + c)
// woff_r[c][o][12] f32 (9 used, pad 12 for float4 alignment)
// xT[b][h][w][c] f32
__global__ __launch_bounds__(256) void k0_prep(
    const float* __restrict__ x,      // [8][64][64][64]
    const float* __restrict__ wconv,  // [64][576]  (576 = c*9+n)
    const float* __restrict__ woff,   // [18][64][9]
    u16* __restrict__ wfrag,          // 4*18*64*8 = 36864 bf16
    float* __restrict__ woff_r,       // 64*216 f32
    float* __restrict__ xT) {         // [8][64][64][64] transposed
  __shared__ float tile[64][65];
  int bid = blockIdx.x;               // grid 512
  int t = threadIdx.x;
  int tid = bid * 256 + t;

  if (tid < 4608) {
    int nt = tid / 1152, ks = (tid / 64) % 18, lane = tid & 63;
    int co = nt * 16 + (lane & 15);
    int n = ks >> 1, s = ks & 1;
    int cl = (lane >> 4) << 3;
    u16* dst = wfrag + tid * 8;
    #pragma unroll
    for (int j = 0; j < 8; ++j) {
      int c = s * 32 + cl + j;
      dst[j] = f2bf(wconv[co * 576 + c * 9 + n]);
    }
  }
  if (tid < 10368) {
    int o = tid / 576, c = (tid / 9) % 64, k = tid % 9;
    woff_r[c * 216 + o * 12 + k] = woff[tid];
  }

  // transpose one (b,h) row-plane: 64 c x 64 w -> 64 w x 64 c
  int bh = ((bid & 7) << 6) | (bid >> 3);   // XCD k -> batch k
  const float* xb = x + (bh >> 6) * 262144 + (bh & 63) * 64;
  int w = t & 63, cr = t >> 6;
  #pragma unroll
  for (int i = 0; i < 16; ++i) {
    int c = cr * 16 + i;
    tile[c][w] = xb[c * 4096 + w];          // coalesced read
  }
  __syncthreads();
  float* dstT = xT + bh * 4096;
  int c2 = t & 63, wr = t >> 6;
  #pragma unroll
  for (int i = 0; i < 16; ++i) {
    int w2 = wr * 16 + i;
    dstT[w2 * 64 + c2] = tile[c2][w2];      // coalesced write, stride-65 LDS read
  }
}

// ---------- k1: offset conv (Phase B), one block per (b,h) ----------
// Wave-uniform woff_r access (s_load path). Writes final offsets incl bias:
// offs_g[bh][o][w] f32, o in [0,18)
__global__ __launch_bounds__(512, 4) void k1_offsets(
    const float* __restrict__ x,        // [8][64][64][64]
    const float* __restrict__ woff_r,   // [64][18][12] f32
    const float* __restrict__ boff,     // [18]
    float* __restrict__ offs_g) {       // [512][18][64]
  __shared__ float part[4608];          // 4 regions x 1152 f32 = 18432B

  int bid = blockIdx.x;
  int b = bid & 7, h = bid >> 3;        // XCD k -> batch k
  int bh = b * 64 + h;
  int t = threadIdx.x;
  int w = t & 63;
  int wv = __builtin_amdgcn_readfirstlane(t >> 6);   // 0..7
  const float* xb = x + b * 262144;

  bool lf = w > 0, rt = w < 63;
  float acc[18];
  #pragma unroll
  for (int o = 0; o < 18; ++o) acc[o] = 0.f;

  for (int cl = 0; cl < 8; ++cl) {
    int c = wv * 8 + cl;
    const float* xc = xb + c * 4096;
    float v[9];
    #pragma unroll
    for (int kh = 0; kh < 3; ++kh) {
      int hh = h + kh - 1;
      bool vr = (hh >= 0 && hh < 64);
      const float* row = xc + hh * 64;
      v[kh * 3 + 0] = (vr && lf) ? row[w - 1] : 0.f;
      v[kh * 3 + 1] = vr         ? row[w]     : 0.f;
      v[kh * 3 + 2] = (vr && rt) ? row[w + 1] : 0.f;
    }
    const float4* wc4 = (const float4*)(woff_r + c * 216);  // wave-uniform -> s_load
    #pragma unroll
    for (int o = 0; o < 18; ++o) {
      float4 wa  = wc4[o * 3 + 0];
      float4 wb  = wc4[o * 3 + 1];
      float4 wcv = wc4[o * 3 + 2];
      acc[o] += v[0]*wa.x + v[1]*wa.y + v[2]*wa.z + v[3]*wa.w
              + v[4]*wb.x + v[5]*wb.y + v[6]*wb.z + v[7]*wb.w
              + v[8]*wcv.x;
    }
  }

  if (wv >= 4) {
    float* reg = part + (wv - 4) * 1152;
    #pragma unroll
    for (int o = 0; o < 18; ++o)
      reg[o * 64 + w] = acc[o];
  }
  __syncthreads();
  if (wv < 4) {
    float* reg = part + wv * 1152;
    #pragma unroll
    for (int o = 0; o < 18; ++o)
      reg[o * 64 + w] += acc[o];
  }
  __syncthreads();
  float* og = offs_g + bh * 1152;
  for (int i = t; i < 1152; i += 512) {
    int o = i >> 6;
    og[i] = boff[o] + part[i] + part[1152 + i] + part[2304 + i] + part[3456 + i];
  }
}

// ---------- k2: sample + GEMM, 2048 blocks x 256 threads ----------
// block = (b, h, wq): 16 w columns. ~7 blocks/CU (LDS 21824B, VGPR<=64).
__global__ __launch_bounds__(256, 8) void k2_sample(
    const float* __restrict__ xT,       // [8][64][64][64] transposed [h][w][c]
    const float* __restrict__ offs_g,   // [512][18][64]
    const u16*  __restrict__ wfrag,     // B-fragments bf16
    float* __restrict__ out) {          // [8][64][64][64]
  __shared__ __align__(16) u16 xos[16 * XOS_STRIDE]; // 18944B xo bf16 [wl][n*64+c]
  __shared__ f4v gw_s[144];                          // 2304B  [n][wl]
  __shared__ u32 qq_s[144];                          //  576B  [n][wl]

  int bid = blockIdx.x;
  int b = bid & 7;                 // XCD k -> batch k
  int r = bid >> 3;                // 0..255
  int h = r >> 2, wq = r & 3;
  int bh = b * 64 + h;
  int t = threadIdx.x;

  // ---- Phase C: corners + bilinear weights for this block's 16 w ----
  if (t < 144) {
    int n  = t >> 4;
    int wl = t & 15;
    int w_g = wq * 16 + wl;
    float ox = offs_g[bh * 1152 + n * 64 + w_g];
    float oy = offs_g[bh * 1152 + (9 + n) * 64 + w_g];
    float px = (float)(h + (n / 3)) + ox;
    float py = (float)(w_g + (n % 3)) + oy;
    float fx = floorf(px), fy = floorf(py);
    float pxc  = fminf(fmaxf(px, 0.f), 65.f);
    float pyc  = fminf(fmaxf(py, 0.f), 65.f);
    float fltx = fminf(fmaxf(fx, 0.f), 65.f);
    float flty = fminf(fmaxf(fy, 0.f), 65.f);
    float frbx = fminf(fmaxf(fx + 1.f, 0.f), 65.f);
    float frby = fminf(fmaxf(fy + 1.f, 0.f), 65.f);
    float ax = 1.f + fltx - pxc, bx = 1.f - frbx + pxc;
    float ay = 1.f + flty - pyc, by = 1.f - frby + pyc;
    float glt = ax * ay, grb = bx * by, glb = ax * by, grt = bx * ay;

    int ilt = (int)fltx, jlt = (int)flty, irb = (int)frbx, jrb = (int)frby;
    bool bi0 = (ilt >= 1 && ilt <= 64), bj0 = (jlt >= 1 && jlt <= 64);
    bool bi1 = (irb >= 1 && irb <= 64), bj1 = (jrb >= 1 && jrb <= 64);
    u32 i0 = bi0 ? (u32)(ilt - 1) : 0u;
    u32 j0 = bj0 ? (u32)(jlt - 1) : 0u;
    u32 i1 = bi1 ? (u32)(irb - 1) : 0u;
    u32 j1 = bj1 ? (u32)(jrb - 1) : 0u;
    f4v gv;
    gv[0] = (bi0 && bj0) ? glt : 0.f;
    gv[1] = (bi1 && bj1) ? grb : 0.f;
    gv[2] = (bi0 && bj1) ? glb : 0.f;
    gv[3] = (bi1 && bj0) ? grt : 0.f;
    gw_s[t] = gv;
    qq_s[t] = i0 | (j0 << 8) | (i1 << 16) | (j1 << 24);
  }
  __syncthreads();

  // ---- sample: c-major mapping. thread: cg = t&15 (c = cg*4), wls = t>>4.
  // 16 consecutive lanes -> 16 consecutive float4 of the same corner row.
  {
    int cg  = t & 15;
    int wls = t >> 4;
    const float* xq = xT + b * 262144 + cg * 4;
    u16* xrow = xos + wls * XOS_STRIDE + cg * 4;
    #pragma unroll
    for (int n = 0; n < 9; ++n) {
      f4v g = gw_s[n * 16 + wls];
      u32 q = qq_s[n * 16 + wls];
      int i0 = (int)(q & 255u) << 12;          // *4096 floats
      int j0 = (int)((q >> 8) & 255u) << 6;    // *64 floats
      int i1 = (int)((q >> 16) & 255u) << 12;
      int j1 = (int)(q >> 24) << 6;
      f4v lt = *(const f4v*)(xq + i0 + j0);
      f4v rb = *(const f4v*)(xq + i1 + j1);
      f4v lb = *(const f4v*)(xq + i0 + j1);
      f4v rt = *(const f4v*)(xq + i1 + j0);
      f4v v  = g[0]*lt + g[1]*rb + g[2]*lb + g[3]*rt;
      s4v pk;
      pk[0] = (short)f2bf(v[0]);
      pk[1] = (short)f2bf(v[1]);
      pk[2] = (short)f2bf(v[2]);
      pk[3] = (short)f2bf(v[3]);
      *(s4v*)(xrow + n * 64) = pk;             // k = n*64 + cg*4
    }
  }
  __syncthreads();

  // ---- GEMM: wave wv owns co-tile wv; 18 K-chunks of 32 ----
  {
    int wv = t >> 6;
    int lane = t & 63;
    int aoff = (lane & 15) * XOS_STRIDE + ((lane >> 4) << 3);
    const s8v* Wf = (const s8v*)wfrag;
    f4v acc = {0.f, 0.f, 0.f, 0.f};
    #pragma unroll
    for (int ks = 0; ks < 18; ++ks) {
      s8v a  = *(const s8v*)(xos + aoff + ks * 32);
      s8v b0 = Wf[(wv * 18 + ks) * 64 + lane];
      acc = __builtin_amdgcn_mfma_f32_16x16x32_bf16(a, b0, acc, 0, 0, 0);
    }
    // store: D layout col=lane&15 (co), row=quad*4+r (w-local)
    int quad = lane >> 4;
    int co = wv * 16 + (lane & 15);
    *(f4v*)(out + b * 262144 + co * 4096 + h * 64 + wq * 16 + quad * 4) = acc;
  }
}

extern "C" void kernel_launch(void* const* d_in, const int* in_sizes, int n_in,
                              void* d_out, int out_size, void* d_ws, size_t ws_size,
                              hipStream_t stream) {
  const float *x = nullptr, *woff = nullptr, *boff = nullptr, *wconv = nullptr;
  for (int i = 0; i < n_in; ++i) {
    switch (in_sizes[i]) {
      case 2097152: x     = (const float*)d_in[i]; break;
      case 10368:   woff  = (const float*)d_in[i]; break;
      case 18:      boff  = (const float*)d_in[i]; break;
      case 36864:   wconv = (const float*)d_in[i]; break;
      default: break;
    }
  }
  if (!x)     x     = (const float*)d_in[0];
  if (!woff)  woff  = (const float*)d_in[1];
  if (!boff)  boff  = (const float*)d_in[2];
  if (!wconv) wconv = (const float*)d_in[3];
  float* out = (float*)d_out;

  u16*   wfrag  = (u16*)d_ws;                        // 73728 B
  float* woff_r = (float*)((char*)d_ws + 73728);     // 55296 B (ends 129024)
  float* xT     = (float*)((char*)d_ws + 131072);    // 8388608 B (ends 8519680)
  float* offs_g = (float*)((char*)d_ws + 8519680);   // 2359296 B (ends 10878976)

  k0_prep<<<512, 256, 0, stream>>>(x, wconv, woff, wfrag, woff_r, xT);
  k1_offsets<<<512, 512, 0, stream>>>(x, woff_r, boff, offs_g);
  k2_sample<<<2048, 256, 0, stream>>>(xT, offs_g, wfrag, out);
}

// Round 4
// 110.403 us; speedup vs baseline: 1.3381x; 1.0443x over previous
//
#include <hip/hip_runtime.h>
#include <hip/hip_bf16.h>

// B=8, C_IN=C_OUT=64, H=W=64, K=3, N=9, PAD=1; padded coords in [0,65]
// f32 in, f32 out.
// R18 = R17 with the launch count cut 3->2 and k2 at full occupancy:
//  - k01: per-(b,h) block (512x512): offset conv (reads woff directly via
//    wave-uniform s_loads; woff_r dropped) + x->xT transpose fused (the conv's
//    center tap IS the transpose input row; stashed in LDS during the conv
//    loop) + wfrag prep in blocks 0..8. Saves one launch/drain + one x pass.
//  - k2_sample: Phase C recomputed inline per sampling thread (no gw_s/qq_s
//    LDS, no pack/unpack, one less __syncthreads). LDS = 18944B -> 8 blocks/CU
//    (32 waves/CU, 100% occupancy). GEMM path identical to R17 (verified).

typedef unsigned int u32;
typedef unsigned short u16;
typedef short s8v __attribute__((ext_vector_type(8)));     // 8 bf16 (4 VGPR)
typedef short s4v __attribute__((ext_vector_type(4)));     // 4 bf16 (2 VGPR)
typedef float f4v __attribute__((ext_vector_type(4)));     // MFMA acc / float4

#define XOS_STRIDE 592   // u16 per w-row (>=576, multiple of 8; 1184B, 16B mult)

__device__ __forceinline__ u16 f2bf(float f) {
  u32 u = __builtin_bit_cast(u32, f);
  u32 r = (u + 0x7FFFu + ((u >> 16) & 1u)) >> 16;   // RNE, finite inputs
  return (u16)r;
}

// ---------- k01: offset conv + transpose + weight prep ----------
// wfrag[nt][ks][lane][j] bf16: B-fragment for mfma_16x16x32_bf16
//   co = nt*16 + (lane&15);  chunk ks: n = ks>>1, s = ks&1,
//   c = s*32 + (lane>>4)*8 + j    (K order: k = n*64 + c)
// offs_g[bh][o][w] f32 (includes bias), xT[b][h][w][c] f32
__global__ __launch_bounds__(512, 4) void k01(
    const float* __restrict__ x,      // [8][64][64][64]
    const float* __restrict__ wconv,  // [64][576]  (576 = c*9+n)
    const float* __restrict__ woff,   // [18][64][9]
    const float* __restrict__ boff,   // [18]
    u16* __restrict__ wfrag,          // 4*18*64*8 = 36864 bf16
    float* __restrict__ offs_g,       // [512][18][64]
    float* __restrict__ xT) {         // [8][64][64][64] transposed
  __shared__ float part[4608];        // 18432B: 4 regions x 1152
  __shared__ float tile[64][65];      // 16640B: transpose staging (+1 pad)

  int bid = blockIdx.x;
  int b = bid & 7, h = bid >> 3;      // XCD k -> batch k
  int bh = b * 64 + h;
  int t = threadIdx.x;
  int w = t & 63;
  int wv = __builtin_amdgcn_readfirstlane(t >> 6);   // 0..7
  const float* xb = x + b * 262144;

  // wfrag prep: blocks 0..8 cover tid < 4608
  int tid = bid * 512 + t;
  if (tid < 4608) {
    int nt = tid / 1152, ks = (tid / 64) % 18, lane = tid & 63;
    int co = nt * 16 + (lane & 15);
    int n = ks >> 1, s = ks & 1;
    int cl8 = (lane >> 4) << 3;
    u16* dst = wfrag + tid * 8;
    #pragma unroll
    for (int j = 0; j < 8; ++j) {
      int c = s * 32 + cl8 + j;
      dst[j] = f2bf(wconv[co * 576 + c * 9 + n]);
    }
  }

  // offset conv: wave wv owns channels [8wv, 8wv+8)
  bool lf = w > 0, rt = w < 63;
  float acc[18];
  #pragma unroll
  for (int o = 0; o < 18; ++o) acc[o] = 0.f;

  for (int cl = 0; cl < 8; ++cl) {
    int c = wv * 8 + cl;
    const float* xc = xb + c * 4096;
    float v[9];
    #pragma unroll
    for (int kh = 0; kh < 3; ++kh) {
      int hh = h + kh - 1;
      bool vr = (hh >= 0 && hh < 64);
      const float* row = xc + hh * 64;
      v[kh * 3 + 0] = (vr && lf) ? row[w - 1] : 0.f;
      v[kh * 3 + 1] = vr         ? row[w]     : 0.f;
      v[kh * 3 + 2] = (vr && rt) ? row[w + 1] : 0.f;
    }
    tile[c][w] = v[4];   // center tap (kh=1 always valid) feeds the transpose
    #pragma unroll
    for (int o = 0; o < 18; ++o) {
      const float* wo = woff + (o * 64 + c) * 9;   // wave-uniform -> s_load
      acc[o] += v[0]*wo[0] + v[1]*wo[1] + v[2]*wo[2] + v[3]*wo[3]
              + v[4]*wo[4] + v[5]*wo[5] + v[6]*wo[6] + v[7]*wo[7]
              + v[8]*wo[8];
    }
  }

  // two-step cross-wave reduction
  if (wv >= 4) {
    float* reg = part + (wv - 4) * 1152;
    #pragma unroll
    for (int o = 0; o < 18; ++o)
      reg[o * 64 + w] = acc[o];
  }
  __syncthreads();
  if (wv < 4) {
    float* reg = part + wv * 1152;
    #pragma unroll
    for (int o = 0; o < 18; ++o)
      reg[o * 64 + w] += acc[o];
  }
  __syncthreads();
  float* og = offs_g + bh * 1152;
  for (int i = t; i < 1152; i += 512) {
    int o = i >> 6;
    og[i] = boff[o] + part[i] + part[1152 + i] + part[2304 + i] + part[3456 + i];
  }

  // transpose write: xT[bh][w][c] (tile fully written before first sync)
  float* dstT = xT + bh * 4096;
  int c2 = t & 63, wr = t >> 6;
  #pragma unroll
  for (int i = 0; i < 8; ++i) {
    int w2 = wr * 8 + i;
    dstT[w2 * 64 + c2] = tile[c2][w2];   // coalesced write, stride-65 LDS read
  }
}

// ---------- k2: sample + GEMM, 2048 blocks x 256 threads, 8 blocks/CU ----------
// block = (b, h, wq): 16 w columns. LDS 18944B, VGPR<=64.
__global__ __launch_bounds__(256, 8) void k2_sample(
    const float* __restrict__ xT,       // [8][64][64][64] transposed [h][w][c]
    const float* __restrict__ offs_g,   // [512][18][64]
    const u16*  __restrict__ wfrag,     // B-fragments bf16
    float* __restrict__ out) {          // [8][64][64][64]
  __shared__ __align__(16) u16 xos[16 * XOS_STRIDE]; // 18944B xo bf16 [wl][n*64+c]

  int bid = blockIdx.x;
  int b = bid & 7;                 // XCD k -> batch k
  int r = bid >> 3;                // 0..255
  int h = r >> 2, wq = r & 3;
  int bh = b * 64 + h;
  int t = threadIdx.x;

  // ---- sample: c-major. thread: cg = t&15 (c = cg*4), wls = t>>4 (w lane).
  // Phase C recomputed inline per thread (16x redundant, ~30 VALU/n — free).
  {
    int cg  = t & 15;
    int wls = t >> 4;
    int w_g = wq * 16 + wls;
    const float* og = offs_g + bh * 1152 + w_g;
    const float* xq = xT + b * 262144 + cg * 4;
    u16* xrow = xos + wls * XOS_STRIDE + cg * 4;
    #pragma unroll
    for (int n = 0; n < 9; ++n) {
      float ox = og[n * 64];
      float oy = og[(9 + n) * 64];
      float px = (float)(h + (n / 3)) + ox;
      float py = (float)(w_g + (n % 3)) + oy;
      float fx = floorf(px), fy = floorf(py);
      float pxc  = fminf(fmaxf(px, 0.f), 65.f);
      float pyc  = fminf(fmaxf(py, 0.f), 65.f);
      float fltx = fminf(fmaxf(fx, 0.f), 65.f);
      float flty = fminf(fmaxf(fy, 0.f), 65.f);
      float frbx = fminf(fmaxf(fx + 1.f, 0.f), 65.f);
      float frby = fminf(fmaxf(fy + 1.f, 0.f), 65.f);
      float ax = 1.f + fltx - pxc, bx = 1.f - frbx + pxc;
      float ay = 1.f + flty - pyc, by = 1.f - frby + pyc;
      float glt = ax * ay, grb = bx * by, glb = ax * by, grt = bx * ay;

      int ilt = (int)fltx, jlt = (int)flty, irb = (int)frbx, jrb = (int)frby;
      bool bi0 = (ilt >= 1 && ilt <= 64), bj0 = (jlt >= 1 && jlt <= 64);
      bool bi1 = (irb >= 1 && irb <= 64), bj1 = (jrb >= 1 && jrb <= 64);
      int i0 = bi0 ? (ilt - 1) : 0;
      int j0 = bj0 ? (jlt - 1) : 0;
      int i1 = bi1 ? (irb - 1) : 0;
      int j1 = bj1 ? (jrb - 1) : 0;
      float g0 = (bi0 && bj0) ? glt : 0.f;
      float g1 = (bi1 && bj1) ? grb : 0.f;
      float g2 = (bi0 && bj1) ? glb : 0.f;
      float g3 = (bi1 && bj0) ? grt : 0.f;

      f4v lt = *(const f4v*)(xq + i0 * 4096 + j0 * 64);
      f4v rb = *(const f4v*)(xq + i1 * 4096 + j1 * 64);
      f4v lb = *(const f4v*)(xq + i0 * 4096 + j1 * 64);
      f4v rt = *(const f4v*)(xq + i1 * 4096 + j0 * 64);
      f4v v  = g0 * lt + g1 * rb + g2 * lb + g3 * rt;
      s4v pk;
      pk[0] = (short)f2bf(v[0]);
      pk[1] = (short)f2bf(v[1]);
      pk[2] = (short)f2bf(v[2]);
      pk[3] = (short)f2bf(v[3]);
      *(s4v*)(xrow + n * 64) = pk;             // k = n*64 + cg*4
    }
  }
  __syncthreads();

  // ---- GEMM: wave wv owns co-tile wv; 18 K-chunks of 32 ----
  {
    int wv = t >> 6;
    int lane = t & 63;
    int aoff = (lane & 15) * XOS_STRIDE + ((lane >> 4) << 3);
    const s8v* Wf = (const s8v*)wfrag;
    f4v acc = {0.f, 0.f, 0.f, 0.f};
    #pragma unroll
    for (int ks = 0; ks < 18; ++ks) {
      s8v a  = *(const s8v*)(xos + aoff + ks * 32);
      s8v b0 = Wf[(wv * 18 + ks) * 64 + lane];
      acc = __builtin_amdgcn_mfma_f32_16x16x32_bf16(a, b0, acc, 0, 0, 0);
    }
    // store: D layout col=lane&15 (co), row=quad*4+r (w-local)
    int quad = lane >> 4;
    int co = wv * 16 + (lane & 15);
    *(f4v*)(out + b * 262144 + co * 4096 + h * 64 + wq * 16 + quad * 4) = acc;
  }
}

extern "C" void kernel_launch(void* const* d_in, const int* in_sizes, int n_in,
                              void* d_out, int out_size, void* d_ws, size_t ws_size,
                              hipStream_t stream) {
  const float *x = nullptr, *woff = nullptr, *boff = nullptr, *wconv = nullptr;
  for (int i = 0; i < n_in; ++i) {
    switch (in_sizes[i]) {
      case 2097152: x     = (const float*)d_in[i]; break;
      case 10368:   woff  = (const float*)d_in[i]; break;
      case 18:      boff  = (const float*)d_in[i]; break;
      case 36864:   wconv = (const float*)d_in[i]; break;
      default: break;
    }
  }
  if (!x)     x     = (const float*)d_in[0];
  if (!woff)  woff  = (const float*)d_in[1];
  if (!boff)  boff  = (const float*)d_in[2];
  if (!wconv) wconv = (const float*)d_in[3];
  float* out = (float*)d_out;

  u16*   wfrag  = (u16*)d_ws;                        // 73728 B
  float* xT     = (float*)((char*)d_ws + 131072);    // 8388608 B (ends 8519680)
  float* offs_g = (float*)((char*)d_ws + 8519680);   // 2359296 B (ends 10878976)

  k01<<<512, 512, 0, stream>>>(x, wconv, woff, boff, wfrag, offs_g, xT);
  k2_sample<<<2048, 256, 0, stream>>>(xT, offs_g, wfrag, out);
}

// Round 6
// 110.365 us; speedup vs baseline: 1.3386x; 1.0003x over previous
//
#include <hip/hip_runtime.h>
#include <hip/hip_bf16.h>

// B=8, C_IN=C_OUT=64, H=W=64, K=3, N=9, PAD=1; padded coords in [0,65]
// f32 in, f32 out.
// R21 = R18 (verified 110.4us) + k2 latency fix. R19/R20's cooperative fusion
// is dead: hipLaunchCooperativeKernel is not graph-capturable (silent no-launch).
// k2 change: VGPR bin 64 -> 128 (__launch_bounds__(256,4); per m69 anything in
// 65..128 gives 4 waves/SIMD) and the sampling loop split into
//   Phase A: all 9 n coordinate/weight sets -> qa[9] (packed corners) + gg[9]
//   Phase B: 9x {unpack addr, 4 float4 L2 loads, combine, cvt, LDS store}
// With addresses precomputed and ~40 spare VGPRs, the compiler can hoist
// corner loads across n-iterations (deep MLP) instead of the R18 serial chain
// (coord math -> addr -> 4 loads -> combine) x9 at zero register headroom.
// k01 and launcher identical to R18.

typedef unsigned int u32;
typedef unsigned short u16;
typedef short s8v __attribute__((ext_vector_type(8)));     // 8 bf16 (4 VGPR)
typedef short s4v __attribute__((ext_vector_type(4)));     // 4 bf16 (2 VGPR)
typedef float f4v __attribute__((ext_vector_type(4)));     // MFMA acc / float4

#define XOS_STRIDE 592   // u16 per w-row (>=576, multiple of 8; 1184B)

__device__ __forceinline__ u16 f2bf(float f) {
  u32 u = __builtin_bit_cast(u32, f);
  u32 r = (u + 0x7FFFu + ((u >> 16) & 1u)) >> 16;   // RNE, finite inputs
  return (u16)r;
}

// ---------- k01: offset conv + transpose + weight prep ----------
// wfrag[nt][ks][lane][j] bf16: B-fragment for mfma_16x16x32_bf16
//   co = nt*16 + (lane&15);  chunk ks: n = ks>>1, s = ks&1,
//   c = s*32 + (lane>>4)*8 + j    (K order: k = n*64 + c)
// offs_g[bh][o][w] f32 (includes bias), xT[b][h][w][c] f32
__global__ __launch_bounds__(512, 4) void k01(
    const float* __restrict__ x,      // [8][64][64][64]
    const float* __restrict__ wconv,  // [64][576]  (576 = c*9+n)
    const float* __restrict__ woff,   // [18][64][9]
    const float* __restrict__ boff,   // [18]
    u16* __restrict__ wfrag,          // 4*18*64*8 = 36864 bf16
    float* __restrict__ offs_g,       // [512][18][64]
    float* __restrict__ xT) {         // [8][64][64][64] transposed
  __shared__ float part[4608];        // 18432B: 4 regions x 1152
  __shared__ float tile[64][65];      // 16640B: transpose staging (+1 pad)

  int bid = blockIdx.x;
  int b = bid & 7, h = bid >> 3;      // XCD k -> batch k
  int bh = b * 64 + h;
  int t = threadIdx.x;
  int w = t & 63;
  int wv = __builtin_amdgcn_readfirstlane(t >> 6);   // 0..7
  const float* xb = x + b * 262144;

  // wfrag prep: blocks 0..8 cover tid < 4608
  int tid = bid * 512 + t;
  if (tid < 4608) {
    int nt = tid / 1152, ks = (tid / 64) % 18, lane = tid & 63;
    int co = nt * 16 + (lane & 15);
    int n = ks >> 1, s = ks & 1;
    int cl8 = (lane >> 4) << 3;
    u16* dst = wfrag + tid * 8;
    #pragma unroll
    for (int j = 0; j < 8; ++j) {
      int c = s * 32 + cl8 + j;
      dst[j] = f2bf(wconv[co * 576 + c * 9 + n]);
    }
  }

  // offset conv: wave wv owns channels [8wv, 8wv+8)
  bool lf = w > 0, rt = w < 63;
  float acc[18];
  #pragma unroll
  for (int o = 0; o < 18; ++o) acc[o] = 0.f;

  for (int cl = 0; cl < 8; ++cl) {
    int c = wv * 8 + cl;
    const float* xc = xb + c * 4096;
    float v[9];
    #pragma unroll
    for (int kh = 0; kh < 3; ++kh) {
      int hh = h + kh - 1;
      bool vr = (hh >= 0 && hh < 64);
      const float* row = xc + hh * 64;
      v[kh * 3 + 0] = (vr && lf) ? row[w - 1] : 0.f;
      v[kh * 3 + 1] = vr         ? row[w]     : 0.f;
      v[kh * 3 + 2] = (vr && rt) ? row[w + 1] : 0.f;
    }
    tile[c][w] = v[4];   // center tap (kh=1 always valid) feeds the transpose
    #pragma unroll
    for (int o = 0; o < 18; ++o) {
      const float* wo = woff + (o * 64 + c) * 9;   // wave-uniform -> s_load
      acc[o] += v[0]*wo[0] + v[1]*wo[1] + v[2]*wo[2] + v[3]*wo[3]
              + v[4]*wo[4] + v[5]*wo[5] + v[6]*wo[6] + v[7]*wo[7]
              + v[8]*wo[8];
    }
  }

  // two-step cross-wave reduction
  if (wv >= 4) {
    float* reg = part + (wv - 4) * 1152;
    #pragma unroll
    for (int o = 0; o < 18; ++o)
      reg[o * 64 + w] = acc[o];
  }
  __syncthreads();
  if (wv < 4) {
    float* reg = part + wv * 1152;
    #pragma unroll
    for (int o = 0; o < 18; ++o)
      reg[o * 64 + w] += acc[o];
  }
  __syncthreads();
  float* og = offs_g + bh * 1152;
  for (int i = t; i < 1152; i += 512) {
    int o = i >> 6;
    og[i] = boff[o] + part[i] + part[1152 + i] + part[2304 + i] + part[3456 + i];
  }

  // transpose write: xT[bh][w][c] (tile fully written before first sync)
  float* dstT = xT + bh * 4096;
  int c2 = t & 63, wr = t >> 6;
  #pragma unroll
  for (int i = 0; i < 8; ++i) {
    int w2 = wr * 8 + i;
    dstT[w2 * 64 + c2] = tile[c2][w2];   // coalesced write, stride-65 LDS read
  }
}

// ---------- k2: sample + GEMM, 2048 blocks x 256 threads ----------
// block = (b, h, wq): 16 w columns. LDS 18944B. __launch_bounds__(256,4):
// VGPR cap 128 (4 waves/SIMD bin) -> compiler can hoist corner loads.
__global__ __launch_bounds__(256, 4) void k2_sample(
    const float* __restrict__ xT,       // [8][64][64][64] transposed [h][w][c]
    const float* __restrict__ offs_g,   // [512][18][64]
    const u16*  __restrict__ wfrag,     // B-fragments bf16
    float* __restrict__ out) {          // [8][64][64][64]
  __shared__ __align__(16) u16 xos[16 * XOS_STRIDE]; // 18944B xo bf16 [wl][n*64+c]

  int bid = blockIdx.x;
  int b = bid & 7;                 // XCD k -> batch k
  int r = bid >> 3;                // 0..255
  int h = r >> 2, wq = r & 3;
  int bh = b * 64 + h;
  int t = threadIdx.x;

  // ---- Phase A: all 9 coordinate/weight sets (no load->coord dependence) ----
  int cg4 = t & 15;                // c = cg4*4
  int wls = t >> 4;                // w lane within tile
  int w_g = wq * 16 + wls;
  u32 qa[9];
  f4v gg[9];
  {
    const float* og = offs_g + bh * 1152 + w_g;
    #pragma unroll
    for (int n = 0; n < 9; ++n) {
      float ox = og[n * 64];
      float oy = og[(9 + n) * 64];
      float px = (float)(h + (n / 3)) + ox;
      float py = (float)(w_g + (n % 3)) + oy;
      float fx = floorf(px), fy = floorf(py);
      float pxc  = fminf(fmaxf(px, 0.f), 65.f);
      float pyc  = fminf(fmaxf(py, 0.f), 65.f);
      float fltx = fminf(fmaxf(fx, 0.f), 65.f);
      float flty = fminf(fmaxf(fy, 0.f), 65.f);
      float frbx = fminf(fmaxf(fx + 1.f, 0.f), 65.f);
      float frby = fminf(fmaxf(fy + 1.f, 0.f), 65.f);
      float ax = 1.f + fltx - pxc, bx = 1.f - frbx + pxc;
      float ay = 1.f + flty - pyc, by = 1.f - frby + pyc;
      float glt = ax * ay, grb = bx * by, glb = ax * by, grt = bx * ay;

      int ilt = (int)fltx, jlt = (int)flty, irb = (int)frbx, jrb = (int)frby;
      bool bi0 = (ilt >= 1 && ilt <= 64), bj0 = (jlt >= 1 && jlt <= 64);
      bool bi1 = (irb >= 1 && irb <= 64), bj1 = (jrb >= 1 && jrb <= 64);
      u32 i0 = bi0 ? (u32)(ilt - 1) : 0u;
      u32 j0 = bj0 ? (u32)(jlt - 1) : 0u;
      u32 i1 = bi1 ? (u32)(irb - 1) : 0u;
      u32 j1 = bj1 ? (u32)(jrb - 1) : 0u;
      qa[n] = i0 | (j0 << 8) | (i1 << 16) | (j1 << 24);
      f4v gv;
      gv[0] = (bi0 && bj0) ? glt : 0.f;
      gv[1] = (bi1 && bj1) ? grb : 0.f;
      gv[2] = (bi0 && bj1) ? glb : 0.f;
      gv[3] = (bi1 && bj0) ? grt : 0.f;
      gg[n] = gv;
    }
  }

  // ---- Phase B: gathers (addresses ready -> compiler pipelines across n) ----
  {
    const float* xq = xT + b * 262144 + cg4 * 4;
    u16* xrow = xos + wls * XOS_STRIDE + cg4 * 4;
    #pragma unroll
    for (int n = 0; n < 9; ++n) {
      u32 q = qa[n];
      f4v g = gg[n];
      int i0 = (int)(q & 255u) << 12;          // *4096 floats
      int j0 = (int)((q >> 8) & 255u) << 6;    // *64 floats
      int i1 = (int)((q >> 16) & 255u) << 12;
      int j1 = (int)(q >> 24) << 6;
      f4v lt = *(const f4v*)(xq + i0 + j0);
      f4v rb = *(const f4v*)(xq + i1 + j1);
      f4v lb = *(const f4v*)(xq + i0 + j1);
      f4v rt = *(const f4v*)(xq + i1 + j0);
      f4v v  = g[0] * lt + g[1] * rb + g[2] * lb + g[3] * rt;
      s4v pk;
      pk[0] = (short)f2bf(v[0]);
      pk[1] = (short)f2bf(v[1]);
      pk[2] = (short)f2bf(v[2]);
      pk[3] = (short)f2bf(v[3]);
      *(s4v*)(xrow + n * 64) = pk;             // k = n*64 + cg4*4
    }
  }
  __syncthreads();

  // ---- GEMM: wave wv owns co-tile wv; 18 K-chunks of 32 ----
  {
    int wv = t >> 6;
    int lane = t & 63;
    int aoff = (lane & 15) * XOS_STRIDE + ((lane >> 4) << 3);
    const s8v* Wf = (const s8v*)wfrag;
    f4v acc = {0.f, 0.f, 0.f, 0.f};
    #pragma unroll
    for (int ks = 0; ks < 18; ++ks) {
      s8v a  = *(const s8v*)(xos + aoff + ks * 32);
      s8v b0 = Wf[(wv * 18 + ks) * 64 + lane];
      acc = __builtin_amdgcn_mfma_f32_16x16x32_bf16(a, b0, acc, 0, 0, 0);
    }
    // store: D layout col=lane&15 (co), row=quad*4+r (w-local)
    int quad = lane >> 4;
    int co = wv * 16 + (lane & 15);
    *(f4v*)(out + b * 262144 + co * 4096 + h * 64 + wq * 16 + quad * 4) = acc;
  }
}

extern "C" void kernel_launch(void* const* d_in, const int* in_sizes, int n_in,
                              void* d_out, int out_size, void* d_ws, size_t ws_size,
                              hipStream_t stream) {
  const float *x = nullptr, *woff = nullptr, *boff = nullptr, *wconv = nullptr;
  for (int i = 0; i < n_in; ++i) {
    switch (in_sizes[i]) {
      case 2097152: x     = (const float*)d_in[i]; break;
      case 10368:   woff  = (const float*)d_in[i]; break;
      case 18:      boff  = (const float*)d_in[i]; break;
      case 36864:   wconv = (const float*)d_in[i]; break;
      default: break;
    }
  }
  if (!x)     x     = (const float*)d_in[0];
  if (!woff)  woff  = (const float*)d_in[1];
  if (!boff)  boff  = (const float*)d_in[2];
  if (!wconv) wconv = (const float*)d_in[3];
  float* out = (float*)d_out;

  u16*   wfrag  = (u16*)d_ws;                        // 73728 B
  float* xT     = (float*)((char*)d_ws + 131072);    // 8388608 B (ends 8519680)
  float* offs_g = (float*)((char*)d_ws + 8519680);   // 2359296 B (ends 10878976)

  k01<<<512, 512, 0, stream>>>(x, wconv, woff, boff, wfrag, offs_g, xT);
  k2_sample<<<2048, 256, 0, stream>>>(xT, offs_g, wfrag, out);
}

// Round 7
// 94.952 us; speedup vs baseline: 1.5559x; 1.1623x over previous
//
#include <hip/hip_runtime.h>
#include <hip/hip_bf16.h>

// B=8, C_IN=C_OUT=64, H=W=64, K=3, N=9, PAD=1; padded coords in [0,65]
// f32 in, f32 out.
// R22: the offset conv becomes an MFMA GEMM inside k2 (it is the same im2col
// as the main conv, with integer taps). Eliminates k01's scalar-weight conv
// (162 s_loads/channel-iter, SGPR-starved serial chains -> the latency hog
// that no busy-counter showed), the cross-wave reduction, and the offs_g
// global round trip.
//  - k01 (prep, 512x256): x->xT transpose + wfrag (main-conv B-fragments) +
//    wofrag (offset-conv B-fragments, o-padded to 32).
//  - k2 (2048x256, lb(256,4)): per (b,h,wq of 16 w):
//      1) integer-tap im2col A-tile (bf16) into LDS  [9 aligned f4 loads/thr]
//      2) wave0: 18-step MFMA x2 chains -> offsets[18][16] (+bias) into LDS
//      3) coords/bilinear weights from offs_lds (regs), bilinear gather
//         overwrites the SAME LDS tile with the main-conv A-tile
//      4) main GEMM (verified R17 path) -> out
// Fragment mappings copied verbatim from the harness-verified main GEMM.

typedef unsigned int u32;
typedef unsigned short u16;
typedef short s8v __attribute__((ext_vector_type(8)));     // 8 bf16 (4 VGPR)
typedef short s4v __attribute__((ext_vector_type(4)));     // 4 bf16 (2 VGPR)
typedef float f4v __attribute__((ext_vector_type(4)));     // MFMA acc / float4

#define XOS_STRIDE 592   // u16 per w-row (>=576, multiple of 8; 1184B)

__device__ __forceinline__ u16 f2bf(float f) {
  u32 u = __builtin_bit_cast(u32, f);
  u32 r = (u + 0x7FFFu + ((u >> 16) & 1u)) >> 16;   // RNE, finite inputs
  return (u16)r;
}

// ---------- k01: transpose + weight fragments ----------
// wfrag[nt][ks][lane][j]  bf16: main-conv B-fragment (co = nt*16+(lane&15))
// wofrag[nt2][ks][lane][j] bf16: offset-conv B-fragment (o = nt2*16+(lane&15),
//   zero-padded for o>=18). Both use K order k = n*64 + c:
//   chunk ks: n = ks>>1, s = ks&1, c = s*32 + (lane>>4)*8 + j.
// xT[b][h][w][c] f32
__global__ __launch_bounds__(256) void k01(
    const float* __restrict__ x,      // [8][64][64][64]
    const float* __restrict__ wconv,  // [64][576]  (576 = c*9+n)
    const float* __restrict__ woff,   // [18][64][9]
    u16* __restrict__ wfrag,          // 4*18*64*8 bf16
    u16* __restrict__ wofrag,         // 2*18*64*8 bf16
    float* __restrict__ xT) {         // [8][64][64][64] transposed
  __shared__ float tile[64][65];
  int bid = blockIdx.x;               // grid 512
  int t = threadIdx.x;
  int tid = bid * 256 + t;

  if (tid < 4608) {
    int nt = tid / 1152, ks = (tid / 64) % 18, lane = tid & 63;
    int co = nt * 16 + (lane & 15);
    int n = ks >> 1, s = ks & 1;
    int cl8 = (lane >> 4) << 3;
    u16* dst = wfrag + tid * 8;
    #pragma unroll
    for (int j = 0; j < 8; ++j) {
      int c = s * 32 + cl8 + j;
      dst[j] = f2bf(wconv[co * 576 + c * 9 + n]);
    }
  }
  if (tid >= 8192 && tid < 10496) {
    int idx = tid - 8192;             // [0, 2304)
    int nt2 = idx / 1152, ks = (idx / 64) % 18, lane = idx & 63;
    int o = nt2 * 16 + (lane & 15);
    int n = ks >> 1, s = ks & 1;
    int cl8 = (lane >> 4) << 3;
    u16* dst = wofrag + idx * 8;
    #pragma unroll
    for (int j = 0; j < 8; ++j) {
      int c = s * 32 + cl8 + j;
      float v = (o < 18) ? woff[(o * 64 + c) * 9 + n] : 0.f;
      dst[j] = f2bf(v);
    }
  }

  // transpose one (b,h) row-plane: 64 c x 64 w -> 64 w x 64 c
  int bh = ((bid & 7) << 6) | (bid >> 3);   // XCD k -> batch k
  const float* xb = x + (bh >> 6) * 262144 + (bh & 63) * 64;
  int w = t & 63, cr = t >> 6;
  #pragma unroll
  for (int i = 0; i < 16; ++i) {
    int c = cr * 16 + i;
    tile[c][w] = xb[c * 4096 + w];          // coalesced read
  }
  __syncthreads();
  float* dstT = xT + bh * 4096;
  int c2 = t & 63, wr = t >> 6;
  #pragma unroll
  for (int i = 0; i < 16; ++i) {
    int w2 = wr * 16 + i;
    dstT[w2 * 64 + c2] = tile[c2][w2];      // coalesced write, stride-65 LDS read
  }
}

// ---------- k2: offset GEMM + sample + main GEMM, 2048 blocks x 256 ----------
// block = (b, h, wq): 16 w columns. LDS 20096B -> 7 blocks/CU.
__global__ __launch_bounds__(256, 4) void k2_sample(
    const float* __restrict__ xT,       // [8][64][64][64] transposed [h][w][c]
    const u16*  __restrict__ wfrag,     // main-conv B-fragments
    const u16*  __restrict__ wofrag,    // offset-conv B-fragments
    const float* __restrict__ boff,     // [18]
    float* __restrict__ out) {          // [8][64][64][64]
  __shared__ __align__(16) u16 xim[16 * XOS_STRIDE]; // 18944B A-tile (reused)
  __shared__ float offs_lds[288];                    // 1152B [o(18)][wl(16)]

  int bid = blockIdx.x;
  int b = bid & 7;                 // XCD k -> batch k
  int r = bid >> 3;                // 0..255
  int h = r >> 2, wq = r & 3;
  int t = threadIdx.x;
  int cg4 = t & 15;                // c = cg4*4
  int wls = t >> 4;                // w lane within tile
  int w_g = wq * 16 + wls;
  const float* xTb = xT + b * 262144;

  // ---- 1) integer-tap im2col A-tile (offset conv inputs), bf16 ----
  {
    const float* xq = xTb + cg4 * 4;
    u16* xrow = xim + wls * XOS_STRIDE + cg4 * 4;
    #pragma unroll
    for (int n = 0; n < 9; ++n) {
      int hh = h + (n / 3) - 1;
      int ww = w_g + (n % 3) - 1;
      f4v v = {0.f, 0.f, 0.f, 0.f};
      if (hh >= 0 && hh < 64 && ww >= 0 && ww < 64)
        v = *(const f4v*)(xq + (hh * 64 + ww) * 64);
      s4v pk;
      pk[0] = (short)f2bf(v[0]);
      pk[1] = (short)f2bf(v[1]);
      pk[2] = (short)f2bf(v[2]);
      pk[3] = (short)f2bf(v[3]);
      *(s4v*)(xrow + n * 64) = pk;         // k = n*64 + cg4*4
    }
  }
  __syncthreads();

  // ---- 2) offset GEMM: wave 0 computes offsets[18][16w] -> offs_lds ----
  if (t < 64) {
    int lane = t;
    int aoff = (lane & 15) * XOS_STRIDE + ((lane >> 4) << 3);
    const s8v* Wo = (const s8v*)wofrag;
    f4v a0 = {0.f, 0.f, 0.f, 0.f}, a1 = {0.f, 0.f, 0.f, 0.f};
    #pragma unroll
    for (int ks = 0; ks < 18; ++ks) {
      s8v a  = *(const s8v*)(xim + aoff + ks * 32);
      a0 = __builtin_amdgcn_mfma_f32_16x16x32_bf16(a, Wo[ks * 64 + lane], a0, 0, 0, 0);
      a1 = __builtin_amdgcn_mfma_f32_16x16x32_bf16(a, Wo[(18 + ks) * 64 + lane], a1, 0, 0, 0);
    }
    // D: col = lane&15 -> o, row = quad*4+reg -> w (same as verified main GEMM)
    int quad = lane >> 4, ol = lane & 15;
    float bo0 = boff[ol];
    #pragma unroll
    for (int r4 = 0; r4 < 4; ++r4)
      offs_lds[ol * 16 + quad * 4 + r4] = a0[r4] + bo0;
    if (ol < 2) {
      float bo1 = boff[16 + ol];
      #pragma unroll
      for (int r4 = 0; r4 < 4; ++r4)
        offs_lds[(16 + ol) * 16 + quad * 4 + r4] = a1[r4] + bo1;
    }
  }
  __syncthreads();   // offsets ready; xim fully read -> safe to overwrite

  // ---- 3) coords + bilinear gather -> overwrite xim with main A-tile ----
  u32 qa[9];
  f4v gg[9];
  {
    #pragma unroll
    for (int n = 0; n < 9; ++n) {
      float ox = offs_lds[n * 16 + wls];
      float oy = offs_lds[(9 + n) * 16 + wls];
      float px = (float)(h + (n / 3)) + ox;
      float py = (float)(w_g + (n % 3)) + oy;
      float fx = floorf(px), fy = floorf(py);
      float pxc  = fminf(fmaxf(px, 0.f), 65.f);
      float pyc  = fminf(fmaxf(py, 0.f), 65.f);
      float fltx = fminf(fmaxf(fx, 0.f), 65.f);
      float flty = fminf(fmaxf(fy, 0.f), 65.f);
      float frbx = fminf(fmaxf(fx + 1.f, 0.f), 65.f);
      float frby = fminf(fmaxf(fy + 1.f, 0.f), 65.f);
      float ax = 1.f + fltx - pxc, bx = 1.f - frbx + pxc;
      float ay = 1.f + flty - pyc, by = 1.f - frby + pyc;
      float glt = ax * ay, grb = bx * by, glb = ax * by, grt = bx * ay;

      int ilt = (int)fltx, jlt = (int)flty, irb = (int)frbx, jrb = (int)frby;
      bool bi0 = (ilt >= 1 && ilt <= 64), bj0 = (jlt >= 1 && jlt <= 64);
      bool bi1 = (irb >= 1 && irb <= 64), bj1 = (jrb >= 1 && jrb <= 64);
      u32 i0 = bi0 ? (u32)(ilt - 1) : 0u;
      u32 j0 = bj0 ? (u32)(jlt - 1) : 0u;
      u32 i1 = bi1 ? (u32)(irb - 1) : 0u;
      u32 j1 = bj1 ? (u32)(jrb - 1) : 0u;
      qa[n] = i0 | (j0 << 8) | (i1 << 16) | (j1 << 24);
      f4v gv;
      gv[0] = (bi0 && bj0) ? glt : 0.f;
      gv[1] = (bi1 && bj1) ? grb : 0.f;
      gv[2] = (bi0 && bj1) ? glb : 0.f;
      gv[3] = (bi1 && bj0) ? grt : 0.f;
      gg[n] = gv;
    }
  }
  {
    const float* xq = xTb + cg4 * 4;
    u16* xrow = xim + wls * XOS_STRIDE + cg4 * 4;
    #pragma unroll
    for (int n = 0; n < 9; ++n) {
      u32 q = qa[n];
      f4v g = gg[n];
      int i0 = (int)(q & 255u) << 12;          // *4096 floats
      int j0 = (int)((q >> 8) & 255u) << 6;    // *64 floats
      int i1 = (int)((q >> 16) & 255u) << 12;
      int j1 = (int)(q >> 24) << 6;
      f4v lt = *(const f4v*)(xq + i0 + j0);
      f4v rb = *(const f4v*)(xq + i1 + j1);
      f4v lb = *(const f4v*)(xq + i0 + j1);
      f4v rt = *(const f4v*)(xq + i1 + j0);
      f4v v  = g[0] * lt + g[1] * rb + g[2] * lb + g[3] * rt;
      s4v pk;
      pk[0] = (short)f2bf(v[0]);
      pk[1] = (short)f2bf(v[1]);
      pk[2] = (short)f2bf(v[2]);
      pk[3] = (short)f2bf(v[3]);
      *(s4v*)(xrow + n * 64) = pk;             // k = n*64 + cg4*4
    }
  }
  __syncthreads();

  // ---- 4) main GEMM: wave wv owns co-tile wv; 18 K-chunks of 32 ----
  {
    int wv = t >> 6;
    int lane = t & 63;
    int aoff = (lane & 15) * XOS_STRIDE + ((lane >> 4) << 3);
    const s8v* Wf = (const s8v*)wfrag;
    f4v acc = {0.f, 0.f, 0.f, 0.f};
    #pragma unroll
    for (int ks = 0; ks < 18; ++ks) {
      s8v a  = *(const s8v*)(xim + aoff + ks * 32);
      s8v b0 = Wf[(wv * 18 + ks) * 64 + lane];
      acc = __builtin_amdgcn_mfma_f32_16x16x32_bf16(a, b0, acc, 0, 0, 0);
    }
    // store: D layout col=lane&15 (co), row=quad*4+r (w-local)
    int quad = lane >> 4;
    int co = wv * 16 + (lane & 15);
    *(f4v*)(out + b * 262144 + co * 4096 + h * 64 + wq * 16 + quad * 4) = acc;
  }
}

extern "C" void kernel_launch(void* const* d_in, const int* in_sizes, int n_in,
                              void* d_out, int out_size, void* d_ws, size_t ws_size,
                              hipStream_t stream) {
  const float *x = nullptr, *woff = nullptr, *boff = nullptr, *wconv = nullptr;
  for (int i = 0; i < n_in; ++i) {
    switch (in_sizes[i]) {
      case 2097152: x     = (const float*)d_in[i]; break;
      case 10368:   woff  = (const float*)d_in[i]; break;
      case 18:      boff  = (const float*)d_in[i]; break;
      case 36864:   wconv = (const float*)d_in[i]; break;
      default: break;
    }
  }
  if (!x)     x     = (const float*)d_in[0];
  if (!woff)  woff  = (const float*)d_in[1];
  if (!boff)  boff  = (const float*)d_in[2];
  if (!wconv) wconv = (const float*)d_in[3];
  float* out = (float*)d_out;

  u16*   wfrag  = (u16*)d_ws;                        // 73728 B
  u16*   wofrag = (u16*)((char*)d_ws + 73728);       // 36864 B (ends 110592)
  float* xT     = (float*)((char*)d_ws + 131072);    // 8388608 B (ends 8519680)

  k01<<<512, 256, 0, stream>>>(x, wconv, woff, wfrag, wofrag, xT);
  k2_sample<<<2048, 256, 0, stream>>>(xT, wfrag, wofrag, boff, out);
}

// Round 8
// 93.794 us; speedup vs baseline: 1.5751x; 1.0123x over previous
//
#include <hip/hip_runtime.h>
#include <hip/hip_bf16.h>

// B=8, C_IN=C_OUT=64, H=W=64, K=3, N=9, PAD=1; padded coords in [0,65]
// f32 in, f32 out.
// R23 = R22 (verified 94.95us, absmax .039) with xT stored as bf16:
//  - halves k2's dominant L2 gather traffic (302->151 MB) and k01's transpose
//    write traffic (8->4 MB)
//  - k2 step 1 (integer im2col) becomes a pure u16x4 copy — bit-identical to
//    R22's f2bf-on-load, so the offset-conv path is numerically unchanged
//  - only the bilinear corners are bf16-rounded before interpolation
//    (predicted absmax .039 -> ~.05, threshold .0856)
// Everything else (offset GEMM on wave0, coord math, main GEMM, fragments)
// identical to R22.

typedef unsigned int u32;
typedef unsigned short u16;
typedef short s8v __attribute__((ext_vector_type(8)));     // 8 bf16 (4 VGPR)
typedef short s4v __attribute__((ext_vector_type(4)));     // 4 bf16 (2 VGPR)
typedef float f4v __attribute__((ext_vector_type(4)));     // MFMA acc / float4

#define XOS_STRIDE 592   // u16 per w-row (>=576, multiple of 8; 1184B)

__device__ __forceinline__ u16 f2bf(float f) {
  u32 u = __builtin_bit_cast(u32, f);
  u32 r = (u + 0x7FFFu + ((u >> 16) & 1u)) >> 16;   // RNE, finite inputs
  return (u16)r;
}

__device__ __forceinline__ f4v bf2f4(s4v v) {
  f4v r;
  r[0] = __builtin_bit_cast(float, ((u32)(u16)v[0]) << 16);
  r[1] = __builtin_bit_cast(float, ((u32)(u16)v[1]) << 16);
  r[2] = __builtin_bit_cast(float, ((u32)(u16)v[2]) << 16);
  r[3] = __builtin_bit_cast(float, ((u32)(u16)v[3]) << 16);
  return r;
}

// ---------- k01: transpose (f32 -> bf16) + weight fragments ----------
// wfrag[nt][ks][lane][j]  bf16: main-conv B-fragment (co = nt*16+(lane&15))
// wofrag[nt2][ks][lane][j] bf16: offset-conv B-fragment (o = nt2*16+(lane&15),
//   zero-padded for o>=18). Both use K order k = n*64 + c:
//   chunk ks: n = ks>>1, s = ks&1, c = s*32 + (lane>>4)*8 + j.
// xT[b][h][w][c] bf16
__global__ __launch_bounds__(256) void k01(
    const float* __restrict__ x,      // [8][64][64][64]
    const float* __restrict__ wconv,  // [64][576]  (576 = c*9+n)
    const float* __restrict__ woff,   // [18][64][9]
    u16* __restrict__ wfrag,          // 4*18*64*8 bf16
    u16* __restrict__ wofrag,         // 2*18*64*8 bf16
    u16* __restrict__ xT) {           // [8][64][64][64] bf16 transposed
  __shared__ float tile[64][65];
  int bid = blockIdx.x;               // grid 512
  int t = threadIdx.x;
  int tid = bid * 256 + t;

  if (tid < 4608) {
    int nt = tid / 1152, ks = (tid / 64) % 18, lane = tid & 63;
    int co = nt * 16 + (lane & 15);
    int n = ks >> 1, s = ks & 1;
    int cl8 = (lane >> 4) << 3;
    u16* dst = wfrag + tid * 8;
    #pragma unroll
    for (int j = 0; j < 8; ++j) {
      int c = s * 32 + cl8 + j;
      dst[j] = f2bf(wconv[co * 576 + c * 9 + n]);
    }
  }
  if (tid >= 8192 && tid < 10496) {
    int idx = tid - 8192;             // [0, 2304)
    int nt2 = idx / 1152, ks = (idx / 64) % 18, lane = idx & 63;
    int o = nt2 * 16 + (lane & 15);
    int n = ks >> 1, s = ks & 1;
    int cl8 = (lane >> 4) << 3;
    u16* dst = wofrag + idx * 8;
    #pragma unroll
    for (int j = 0; j < 8; ++j) {
      int c = s * 32 + cl8 + j;
      float v = (o < 18) ? woff[(o * 64 + c) * 9 + n] : 0.f;
      dst[j] = f2bf(v);
    }
  }

  // transpose one (b,h) row-plane: 64 c x 64 w f32 -> 64 w x 64 c bf16
  int bh = ((bid & 7) << 6) | (bid >> 3);   // XCD k -> batch k
  const float* xb = x + (bh >> 6) * 262144 + (bh & 63) * 64;
  int w = t & 63, cr = t >> 6;
  #pragma unroll
  for (int i = 0; i < 16; ++i) {
    int c = cr * 16 + i;
    tile[c][w] = xb[c * 4096 + w];          // coalesced read
  }
  __syncthreads();
  // write bf16 pairs: lane c2 covers c = {2*c2, 2*c2+1}; 32 lanes = 128B/w-row
  u32* dstT = (u32*)(xT + bh * 4096);       // u32 = 2 bf16
  int c2 = t & 31, wr = t >> 5;             // wr in [0,8)
  #pragma unroll
  for (int i = 0; i < 8; ++i) {
    int w2 = wr * 8 + i;
    u32 lo = f2bf(tile[c2 * 2][w2]);
    u32 hi = f2bf(tile[c2 * 2 + 1][w2]);
    dstT[w2 * 32 + c2] = lo | (hi << 16);   // coalesced, 2-way LDS free
  }
}

// ---------- k2: offset GEMM + sample + main GEMM, 2048 blocks x 256 ----------
// block = (b, h, wq): 16 w columns. LDS 20096B -> 8 blocks/CU.
__global__ __launch_bounds__(256, 4) void k2_sample(
    const u16*  __restrict__ xT,        // [8][64][64][64] bf16 [h][w][c]
    const u16*  __restrict__ wfrag,     // main-conv B-fragments
    const u16*  __restrict__ wofrag,    // offset-conv B-fragments
    const float* __restrict__ boff,     // [18]
    float* __restrict__ out) {          // [8][64][64][64]
  __shared__ __align__(16) u16 xim[16 * XOS_STRIDE]; // 18944B A-tile (reused)
  __shared__ float offs_lds[288];                    // 1152B [o(18)][wl(16)]

  int bid = blockIdx.x;
  int b = bid & 7;                 // XCD k -> batch k
  int r = bid >> 3;                // 0..255
  int h = r >> 2, wq = r & 3;
  int t = threadIdx.x;
  int cg4 = t & 15;                // c = cg4*4
  int wls = t >> 4;                // w lane within tile
  int w_g = wq * 16 + wls;
  const u16* xTb = xT + b * 262144;

  // ---- 1) integer-tap im2col A-tile: pure bf16 copy (== R22's f2bf path) ----
  {
    const u16* xq = xTb + cg4 * 4;
    u16* xrow = xim + wls * XOS_STRIDE + cg4 * 4;
    #pragma unroll
    for (int n = 0; n < 9; ++n) {
      int hh = h + (n / 3) - 1;
      int ww = w_g + (n % 3) - 1;
      s4v v = {0, 0, 0, 0};
      if (hh >= 0 && hh < 64 && ww >= 0 && ww < 64)
        v = *(const s4v*)(xq + (hh * 64 + ww) * 64);
      *(s4v*)(xrow + n * 64) = v;          // k = n*64 + cg4*4
    }
  }
  __syncthreads();

  // ---- 2) offset GEMM: wave 0 computes offsets[18][16w] -> offs_lds ----
  if (t < 64) {
    int lane = t;
    int aoff = (lane & 15) * XOS_STRIDE + ((lane >> 4) << 3);
    const s8v* Wo = (const s8v*)wofrag;
    f4v a0 = {0.f, 0.f, 0.f, 0.f}, a1 = {0.f, 0.f, 0.f, 0.f};
    #pragma unroll
    for (int ks = 0; ks < 18; ++ks) {
      s8v a  = *(const s8v*)(xim + aoff + ks * 32);
      a0 = __builtin_amdgcn_mfma_f32_16x16x32_bf16(a, Wo[ks * 64 + lane], a0, 0, 0, 0);
      a1 = __builtin_amdgcn_mfma_f32_16x16x32_bf16(a, Wo[(18 + ks) * 64 + lane], a1, 0, 0, 0);
    }
    // D: col = lane&15 -> o, row = quad*4+reg -> w (same as verified main GEMM)
    int quad = lane >> 4, ol = lane & 15;
    float bo0 = boff[ol];
    #pragma unroll
    for (int r4 = 0; r4 < 4; ++r4)
      offs_lds[ol * 16 + quad * 4 + r4] = a0[r4] + bo0;
    if (ol < 2) {
      float bo1 = boff[16 + ol];
      #pragma unroll
      for (int r4 = 0; r4 < 4; ++r4)
        offs_lds[(16 + ol) * 16 + quad * 4 + r4] = a1[r4] + bo1;
    }
  }
  __syncthreads();   // offsets ready; xim fully read -> safe to overwrite

  // ---- 3) coords + bilinear gather -> overwrite xim with main A-tile ----
  u32 qa[9];
  f4v gg[9];
  {
    #pragma unroll
    for (int n = 0; n < 9; ++n) {
      float ox = offs_lds[n * 16 + wls];
      float oy = offs_lds[(9 + n) * 16 + wls];
      float px = (float)(h + (n / 3)) + ox;
      float py = (float)(w_g + (n % 3)) + oy;
      float fx = floorf(px), fy = floorf(py);
      float pxc  = fminf(fmaxf(px, 0.f), 65.f);
      float pyc  = fminf(fmaxf(py, 0.f), 65.f);
      float fltx = fminf(fmaxf(fx, 0.f), 65.f);
      float flty = fminf(fmaxf(fy, 0.f), 65.f);
      float frbx = fminf(fmaxf(fx + 1.f, 0.f), 65.f);
      float frby = fminf(fmaxf(fy + 1.f, 0.f), 65.f);
      float ax = 1.f + fltx - pxc, bx = 1.f - frbx + pxc;
      float ay = 1.f + flty - pyc, by = 1.f - frby + pyc;
      float glt = ax * ay, grb = bx * by, glb = ax * by, grt = bx * ay;

      int ilt = (int)fltx, jlt = (int)flty, irb = (int)frbx, jrb = (int)frby;
      bool bi0 = (ilt >= 1 && ilt <= 64), bj0 = (jlt >= 1 && jlt <= 64);
      bool bi1 = (irb >= 1 && irb <= 64), bj1 = (jrb >= 1 && jrb <= 64);
      u32 i0 = bi0 ? (u32)(ilt - 1) : 0u;
      u32 j0 = bj0 ? (u32)(jlt - 1) : 0u;
      u32 i1 = bi1 ? (u32)(irb - 1) : 0u;
      u32 j1 = bj1 ? (u32)(jrb - 1) : 0u;
      qa[n] = i0 | (j0 << 8) | (i1 << 16) | (j1 << 24);
      f4v gv;
      gv[0] = (bi0 && bj0) ? glt : 0.f;
      gv[1] = (bi1 && bj1) ? grb : 0.f;
      gv[2] = (bi0 && bj1) ? glb : 0.f;
      gv[3] = (bi1 && bj0) ? grt : 0.f;
      gg[n] = gv;
    }
  }
  {
    const u16* xq = xTb + cg4 * 4;
    u16* xrow = xim + wls * XOS_STRIDE + cg4 * 4;
    #pragma unroll
    for (int n = 0; n < 9; ++n) {
      u32 q = qa[n];
      f4v g = gg[n];
      int i0 = (int)(q & 255u) << 12;          // *4096 u16 (row stride 64*64)
      int j0 = (int)((q >> 8) & 255u) << 6;    // *64 u16
      int i1 = (int)((q >> 16) & 255u) << 12;
      int j1 = (int)(q >> 24) << 6;
      f4v lt = bf2f4(*(const s4v*)(xq + i0 + j0));
      f4v rb = bf2f4(*(const s4v*)(xq + i1 + j1));
      f4v lb = bf2f4(*(const s4v*)(xq + i0 + j1));
      f4v rt = bf2f4(*(const s4v*)(xq + i1 + j0));
      f4v v  = g[0] * lt + g[1] * rb + g[2] * lb + g[3] * rt;
      s4v pk;
      pk[0] = (short)f2bf(v[0]);
      pk[1] = (short)f2bf(v[1]);
      pk[2] = (short)f2bf(v[2]);
      pk[3] = (short)f2bf(v[3]);
      *(s4v*)(xrow + n * 64) = pk;             // k = n*64 + cg4*4
    }
  }
  __syncthreads();

  // ---- 4) main GEMM: wave wv owns co-tile wv; 18 K-chunks of 32 ----
  {
    int wv = t >> 6;
    int lane = t & 63;
    int aoff = (lane & 15) * XOS_STRIDE + ((lane >> 4) << 3);
    const s8v* Wf = (const s8v*)wfrag;
    f4v acc = {0.f, 0.f, 0.f, 0.f};
    #pragma unroll
    for (int ks = 0; ks < 18; ++ks) {
      s8v a  = *(const s8v*)(xim + aoff + ks * 32);
      s8v b0 = Wf[(wv * 18 + ks) * 64 + lane];
      acc = __builtin_amdgcn_mfma_f32_16x16x32_bf16(a, b0, acc, 0, 0, 0);
    }
    // store: D layout col=lane&15 (co), row=quad*4+r (w-local)
    int quad = lane >> 4;
    int co = wv * 16 + (lane & 15);
    *(f4v*)(out + b * 262144 + co * 4096 + h * 64 + wq * 16 + quad * 4) = acc;
  }
}

extern "C" void kernel_launch(void* const* d_in, const int* in_sizes, int n_in,
                              void* d_out, int out_size, void* d_ws, size_t ws_size,
                              hipStream_t stream) {
  const float *x = nullptr, *woff = nullptr, *boff = nullptr, *wconv = nullptr;
  for (int i = 0; i < n_in; ++i) {
    switch (in_sizes[i]) {
      case 2097152: x     = (const float*)d_in[i]; break;
      case 10368:   woff  = (const float*)d_in[i]; break;
      case 18:      boff  = (const float*)d_in[i]; break;
      case 36864:   wconv = (const float*)d_in[i]; break;
      default: break;
    }
  }
  if (!x)     x     = (const float*)d_in[0];
  if (!woff)  woff  = (const float*)d_in[1];
  if (!boff)  boff  = (const float*)d_in[2];
  if (!wconv) wconv = (const float*)d_in[3];
  float* out = (float*)d_out;

  u16* wfrag  = (u16*)d_ws;                        // 73728 B
  u16* wofrag = (u16*)((char*)d_ws + 73728);       // 36864 B (ends 110592)
  u16* xT     = (u16*)((char*)d_ws + 131072);      // 4194304 B bf16 (ends 4325376)

  k01<<<512, 256, 0, stream>>>(x, wconv, woff, wfrag, wofrag, xT);
  k2_sample<<<2048, 256, 0, stream>>>(xT, wfrag, wofrag, boff, out);
}

// Round 10
// 92.158 us; speedup vs baseline: 1.6030x; 1.0178x over previous
//
#include <hip/hip_runtime.h>
#include <hip/hip_bf16.h>

// B=8, C_IN=C_OUT=64, H=W=64, K=3, N=9, PAD=1; padded coords in [0,65]
// f32 in, f32 out.
// R25 = R24 resubmitted verbatim (R9 bench was an infra failure: container
// died twice; kernel never ran). Rationale recap:
//  - M=32 per block (1024 blocks x 256 thr): each wfrag B-fragment loaded once,
//    used for TWO MFMAs (two 16-w subtiles) -> wfrag L2 traffic 147->74MB,
//    wofrag 74->37MB; offset GEMM on waves 0 AND 1 (one subtile each);
//    half the barriers per unit work. LDS 37376+2304=39680B -> 4 blocks/CU.
//  - XOS_STRIDE 592->584: row stride 1168B, (292 mod 32)=4 -> ds_read_b128
//    A-reads are 2-way bank-aliased (free, m136) instead of 592's 4-way (1.58x).
//  - k01 identical to R23. All arithmetic unchanged -> absmax .0390625.

typedef unsigned int u32;
typedef unsigned short u16;
typedef short s8v __attribute__((ext_vector_type(8)));     // 8 bf16 (4 VGPR)
typedef short s4v __attribute__((ext_vector_type(4)));     // 4 bf16 (2 VGPR)
typedef float f4v __attribute__((ext_vector_type(4)));     // MFMA acc / float4

#define XOS_STRIDE 584   // u16 per w-row (>=576, x2 = 1168B, mult of 16)

__device__ __forceinline__ u16 f2bf(float f) {
  u32 u = __builtin_bit_cast(u32, f);
  u32 r = (u + 0x7FFFu + ((u >> 16) & 1u)) >> 16;   // RNE, finite inputs
  return (u16)r;
}

__device__ __forceinline__ f4v bf2f4(s4v v) {
  f4v r;
  r[0] = __builtin_bit_cast(float, ((u32)(u16)v[0]) << 16);
  r[1] = __builtin_bit_cast(float, ((u32)(u16)v[1]) << 16);
  r[2] = __builtin_bit_cast(float, ((u32)(u16)v[2]) << 16);
  r[3] = __builtin_bit_cast(float, ((u32)(u16)v[3]) << 16);
  return r;
}

// ---------- k01: transpose (f32 -> bf16) + weight fragments ----------
// wfrag[nt][ks][lane][j]  bf16: main-conv B-fragment (co = nt*16+(lane&15))
// wofrag[nt2][ks][lane][j] bf16: offset-conv B-fragment (o = nt2*16+(lane&15),
//   zero-padded for o>=18). Both use K order k = n*64 + c:
//   chunk ks: n = ks>>1, s = ks&1, c = s*32 + (lane>>4)*8 + j.
// xT[b][h][w][c] bf16
__global__ __launch_bounds__(256) void k01(
    const float* __restrict__ x,      // [8][64][64][64]
    const float* __restrict__ wconv,  // [64][576]  (576 = c*9+n)
    const float* __restrict__ woff,   // [18][64][9]
    u16* __restrict__ wfrag,          // 4*18*64*8 bf16
    u16* __restrict__ wofrag,         // 2*18*64*8 bf16
    u16* __restrict__ xT) {           // [8][64][64][64] bf16 transposed
  __shared__ float tile[64][65];
  int bid = blockIdx.x;               // grid 512
  int t = threadIdx.x;
  int tid = bid * 256 + t;

  if (tid < 4608) {
    int nt = tid / 1152, ks = (tid / 64) % 18, lane = tid & 63;
    int co = nt * 16 + (lane & 15);
    int n = ks >> 1, s = ks & 1;
    int cl8 = (lane >> 4) << 3;
    u16* dst = wfrag + tid * 8;
    #pragma unroll
    for (int j = 0; j < 8; ++j) {
      int c = s * 32 + cl8 + j;
      dst[j] = f2bf(wconv[co * 576 + c * 9 + n]);
    }
  }
  if (tid >= 8192 && tid < 10496) {
    int idx = tid - 8192;             // [0, 2304)
    int nt2 = idx / 1152, ks = (idx / 64) % 18, lane = idx & 63;
    int o = nt2 * 16 + (lane & 15);
    int n = ks >> 1, s = ks & 1;
    int cl8 = (lane >> 4) << 3;
    u16* dst = wofrag + idx * 8;
    #pragma unroll
    for (int j = 0; j < 8; ++j) {
      int c = s * 32 + cl8 + j;
      float v = (o < 18) ? woff[(o * 64 + c) * 9 + n] : 0.f;
      dst[j] = f2bf(v);
    }
  }

  // transpose one (b,h) row-plane: 64 c x 64 w f32 -> 64 w x 64 c bf16
  int bh = ((bid & 7) << 6) | (bid >> 3);   // XCD k -> batch k
  const float* xb = x + (bh >> 6) * 262144 + (bh & 63) * 64;
  int w = t & 63, cr = t >> 6;
  #pragma unroll
  for (int i = 0; i < 16; ++i) {
    int c = cr * 16 + i;
    tile[c][w] = xb[c * 4096 + w];          // coalesced read
  }
  __syncthreads();
  // write bf16 pairs: lane c2 covers c = {2*c2, 2*c2+1}; 32 lanes = 128B/w-row
  u32* dstT = (u32*)(xT + bh * 4096);       // u32 = 2 bf16
  int c2 = t & 31, wr = t >> 5;             // wr in [0,8)
  #pragma unroll
  for (int i = 0; i < 8; ++i) {
    int w2 = wr * 8 + i;
    u32 lo = f2bf(tile[c2 * 2][w2]);
    u32 hi = f2bf(tile[c2 * 2 + 1][w2]);
    dstT[w2 * 32 + c2] = lo | (hi << 16);   // coalesced, 2-way LDS free
  }
}

// ---------- k2: offset GEMM + sample + main GEMM, 1024 blocks x 256 ----------
// block = (b, h, wh): 32 w columns (2 subtiles of 16). LDS 39680B -> 4 blk/CU.
__global__ __launch_bounds__(256, 4) void k2_sample(
    const u16*  __restrict__ xT,        // [8][64][64][64] bf16 [h][w][c]
    const u16*  __restrict__ wfrag,     // main-conv B-fragments
    const u16*  __restrict__ wofrag,    // offset-conv B-fragments
    const float* __restrict__ boff,     // [18]
    float* __restrict__ out) {          // [8][64][64][64]
  __shared__ __align__(16) u16 xim[32 * XOS_STRIDE]; // 37376B A-tile (reused)
  __shared__ float offs_lds[576];                    // 2304B [o(18)][wl(32)]

  int bid = blockIdx.x;
  int b = bid & 7;                 // XCD k -> batch k
  int r = bid >> 3;                // 0..127
  int h = r >> 1, wh = r & 1;      // wh: which 32-w half
  int t = threadIdx.x;
  int cg4 = t & 15;                // c = cg4*4
  int wls = t >> 4;                // 0..15 (w lane within a 16-subtile)
  const u16* xTb = xT + b * 262144;

  // ---- 1) integer-tap im2col A-tile (both subtiles): pure bf16 copy ----
  #pragma unroll
  for (int it = 0; it < 2; ++it) {
    int wl = wls + 16 * it;
    int w_g = wh * 32 + wl;
    const u16* xq = xTb + cg4 * 4;
    u16* xrow = xim + wl * XOS_STRIDE + cg4 * 4;
    #pragma unroll
    for (int n = 0; n < 9; ++n) {
      int hh = h + (n / 3) - 1;
      int ww = w_g + (n % 3) - 1;
      s4v v = {0, 0, 0, 0};
      if (hh >= 0 && hh < 64 && ww >= 0 && ww < 64)
        v = *(const s4v*)(xq + (hh * 64 + ww) * 64);
      *(s4v*)(xrow + n * 64) = v;          // k = n*64 + cg4*4
    }
  }
  __syncthreads();

  // ---- 2) offset GEMM: waves 0,1 -> offsets[18][32w] (wave wv = subtile wv) ----
  {
    int wv = t >> 6;
    int lane = t & 63;
    if (wv < 2) {
      int aoff = ((lane & 15) + 16 * wv) * XOS_STRIDE + ((lane >> 4) << 3);
      const s8v* Wo = (const s8v*)wofrag;
      f4v a0 = {0.f, 0.f, 0.f, 0.f}, a1 = {0.f, 0.f, 0.f, 0.f};
      #pragma unroll
      for (int ks = 0; ks < 18; ++ks) {
        s8v a  = *(const s8v*)(xim + aoff + ks * 32);
        a0 = __builtin_amdgcn_mfma_f32_16x16x32_bf16(a, Wo[ks * 64 + lane], a0, 0, 0, 0);
        a1 = __builtin_amdgcn_mfma_f32_16x16x32_bf16(a, Wo[(18 + ks) * 64 + lane], a1, 0, 0, 0);
      }
      // D: col = lane&15 -> o, row = quad*4+reg -> w-in-subtile
      int quad = lane >> 4, ol = lane & 15;
      float bo0 = boff[ol];
      #pragma unroll
      for (int r4 = 0; r4 < 4; ++r4)
        offs_lds[ol * 32 + wv * 16 + quad * 4 + r4] = a0[r4] + bo0;
      if (ol < 2) {
        float bo1 = boff[16 + ol];
        #pragma unroll
        for (int r4 = 0; r4 < 4; ++r4)
          offs_lds[(16 + ol) * 32 + wv * 16 + quad * 4 + r4] = a1[r4] + bo1;
      }
    }
  }
  __syncthreads();   // offsets ready; xim fully read -> safe to overwrite

  // ---- 3) coords + bilinear gather -> overwrite xim with main A-tile ----
  #pragma unroll
  for (int it = 0; it < 2; ++it) {
    int wl = wls + 16 * it;
    int w_g = wh * 32 + wl;
    u32 qa[9];
    f4v gg[9];
    #pragma unroll
    for (int n = 0; n < 9; ++n) {
      float ox = offs_lds[n * 32 + wl];
      float oy = offs_lds[(9 + n) * 32 + wl];
      float px = (float)(h + (n / 3)) + ox;
      float py = (float)(w_g + (n % 3)) + oy;
      float fx = floorf(px), fy = floorf(py);
      float pxc  = fminf(fmaxf(px, 0.f), 65.f);
      float pyc  = fminf(fmaxf(py, 0.f), 65.f);
      float fltx = fminf(fmaxf(fx, 0.f), 65.f);
      float flty = fminf(fmaxf(fy, 0.f), 65.f);
      float frbx = fminf(fmaxf(fx + 1.f, 0.f), 65.f);
      float frby = fminf(fmaxf(fy + 1.f, 0.f), 65.f);
      float ax = 1.f + fltx - pxc, bx = 1.f - frbx + pxc;
      float ay = 1.f + flty - pyc, by = 1.f - frby + pyc;
      float glt = ax * ay, grb = bx * by, glb = ax * by, grt = bx * ay;

      int ilt = (int)fltx, jlt = (int)flty, irb = (int)frbx, jrb = (int)frby;
      bool bi0 = (ilt >= 1 && ilt <= 64), bj0 = (jlt >= 1 && jlt <= 64);
      bool bi1 = (irb >= 1 && irb <= 64), bj1 = (jrb >= 1 && jrb <= 64);
      u32 i0 = bi0 ? (u32)(ilt - 1) : 0u;
      u32 j0 = bj0 ? (u32)(jlt - 1) : 0u;
      u32 i1 = bi1 ? (u32)(irb - 1) : 0u;
      u32 j1 = bj1 ? (u32)(jrb - 1) : 0u;
      qa[n] = i0 | (j0 << 8) | (i1 << 16) | (j1 << 24);
      f4v gv;
      gv[0] = (bi0 && bj0) ? glt : 0.f;
      gv[1] = (bi1 && bj1) ? grb : 0.f;
      gv[2] = (bi0 && bj1) ? glb : 0.f;
      gv[3] = (bi1 && bj0) ? grt : 0.f;
      gg[n] = gv;
    }
    const u16* xq = xTb + cg4 * 4;
    u16* xrow = xim + wl * XOS_STRIDE + cg4 * 4;
    #pragma unroll
    for (int n = 0; n < 9; ++n) {
      u32 q = qa[n];
      f4v g = gg[n];
      int i0 = (int)(q & 255u) << 12;          // *4096 u16 (row stride 64*64)
      int j0 = (int)((q >> 8) & 255u) << 6;    // *64 u16
      int i1 = (int)((q >> 16) & 255u) << 12;
      int j1 = (int)(q >> 24) << 6;
      f4v lt = bf2f4(*(const s4v*)(xq + i0 + j0));
      f4v rb = bf2f4(*(const s4v*)(xq + i1 + j1));
      f4v lb = bf2f4(*(const s4v*)(xq + i0 + j1));
      f4v rt = bf2f4(*(const s4v*)(xq + i1 + j0));
      f4v v  = g[0] * lt + g[1] * rb + g[2] * lb + g[3] * rt;
      s4v pk;
      pk[0] = (short)f2bf(v[0]);
      pk[1] = (short)f2bf(v[1]);
      pk[2] = (short)f2bf(v[2]);
      pk[3] = (short)f2bf(v[3]);
      *(s4v*)(xrow + n * 64) = pk;             // k = n*64 + cg4*4
    }
  }
  __syncthreads();

  // ---- 4) main GEMM: wave wv owns co-tile wv; B loaded once, used twice ----
  {
    int wv = t >> 6;
    int lane = t & 63;
    int aoff0 = (lane & 15) * XOS_STRIDE + ((lane >> 4) << 3);
    int aoff1 = aoff0 + 16 * XOS_STRIDE;
    const s8v* Wf = (const s8v*)wfrag;
    f4v acc0 = {0.f, 0.f, 0.f, 0.f}, acc1 = {0.f, 0.f, 0.f, 0.f};
    #pragma unroll
    for (int ks = 0; ks < 18; ++ks) {
      s8v b0 = Wf[(wv * 18 + ks) * 64 + lane];
      s8v a0 = *(const s8v*)(xim + aoff0 + ks * 32);
      s8v a1 = *(const s8v*)(xim + aoff1 + ks * 32);
      acc0 = __builtin_amdgcn_mfma_f32_16x16x32_bf16(a0, b0, acc0, 0, 0, 0);
      acc1 = __builtin_amdgcn_mfma_f32_16x16x32_bf16(a1, b0, acc1, 0, 0, 0);
    }
    // store: D layout col=lane&15 (co), row=quad*4+r (w-local)
    int quad = lane >> 4;
    int co = wv * 16 + (lane & 15);
    float* ob = out + b * 262144 + co * 4096 + h * 64 + wh * 32;
    *(f4v*)(ob + quad * 4)      = acc0;
    *(f4v*)(ob + 16 + quad * 4) = acc1;
  }
}

extern "C" void kernel_launch(void* const* d_in, const int* in_sizes, int n_in,
                              void* d_out, int out_size, void* d_ws, size_t ws_size,
                              hipStream_t stream) {
  const float *x = nullptr, *woff = nullptr, *boff = nullptr, *wconv = nullptr;
  for (int i = 0; i < n_in; ++i) {
    switch (in_sizes[i]) {
      case 2097152: x     = (const float*)d_in[i]; break;
      case 10368:   woff  = (const float*)d_in[i]; break;
      case 18:      boff  = (const float*)d_in[i]; break;
      case 36864:   wconv = (const float*)d_in[i]; break;
      default: break;
    }
  }
  if (!x)     x     = (const float*)d_in[0];
  if (!woff)  woff  = (const float*)d_in[1];
  if (!boff)  boff  = (const float*)d_in[2];
  if (!wconv) wconv = (const float*)d_in[3];
  float* out = (float*)d_out;

  u16* wfrag  = (u16*)d_ws;                        // 73728 B
  u16* wofrag = (u16*)((char*)d_ws + 73728);       // 36864 B (ends 110592)
  u16* xT     = (u16*)((char*)d_ws + 131072);      // 4194304 B bf16 (ends 4325376)

  k01<<<512, 256, 0, stream>>>(x, wconv, woff, wfrag, wofrag, xT);
  k2_sample<<<1024, 256, 0, stream>>>(xT, wfrag, wofrag, boff, out);
}

// Round 11
// 92.121 us; speedup vs baseline: 1.6037x; 1.0004x over previous
//
#include <hip/hip_runtime.h>
#include <hip/hip_bf16.h>

// B=8, C_IN=C_OUT=64, H=W=64, K=3, N=9, PAD=1; padded coords in [0,65]
// f32 in, f32 out.
// R26 = R25 (verified 92.2us, absmax .0390625) with step-1 im2col staging
// DELETED: the offset GEMM's A-fragments (k = n*64+c, 8 consecutive c at a
// fixed integer tap n) are 16B-contiguous slices of xT, so waves 0-1 load
// them directly from global with border predication — bit-identical values.
// Removes: the 32x576 LDS staging by all 256 threads (75MB L2 traffic across
// the grid), 18 ds_writes/thread, step-2's ds_reads, and one of three
// __syncthreads. Steps 3/4 and k01 unchanged. absmax must stay .0390625.

typedef unsigned int u32;
typedef unsigned short u16;
typedef short s8v __attribute__((ext_vector_type(8)));     // 8 bf16 (4 VGPR)
typedef short s4v __attribute__((ext_vector_type(4)));     // 4 bf16 (2 VGPR)
typedef float f4v __attribute__((ext_vector_type(4)));     // MFMA acc / float4

#define XOS_STRIDE 584   // u16 per w-row (1168B; 16B-granule uniform -> b128 conflict-free)

__device__ __forceinline__ u16 f2bf(float f) {
  u32 u = __builtin_bit_cast(u32, f);
  u32 r = (u + 0x7FFFu + ((u >> 16) & 1u)) >> 16;   // RNE, finite inputs
  return (u16)r;
}

__device__ __forceinline__ f4v bf2f4(s4v v) {
  f4v r;
  r[0] = __builtin_bit_cast(float, ((u32)(u16)v[0]) << 16);
  r[1] = __builtin_bit_cast(float, ((u32)(u16)v[1]) << 16);
  r[2] = __builtin_bit_cast(float, ((u32)(u16)v[2]) << 16);
  r[3] = __builtin_bit_cast(float, ((u32)(u16)v[3]) << 16);
  return r;
}

// ---------- k01: transpose (f32 -> bf16) + weight fragments ----------
// wfrag[nt][ks][lane][j]  bf16: main-conv B-fragment (co = nt*16+(lane&15))
// wofrag[nt2][ks][lane][j] bf16: offset-conv B-fragment (o = nt2*16+(lane&15),
//   zero-padded for o>=18). Both use K order k = n*64 + c:
//   chunk ks: n = ks>>1, s = ks&1, c = s*32 + (lane>>4)*8 + j.
// xT[b][h][w][c] bf16
__global__ __launch_bounds__(256) void k01(
    const float* __restrict__ x,      // [8][64][64][64]
    const float* __restrict__ wconv,  // [64][576]  (576 = c*9+n)
    const float* __restrict__ woff,   // [18][64][9]
    u16* __restrict__ wfrag,          // 4*18*64*8 bf16
    u16* __restrict__ wofrag,         // 2*18*64*8 bf16
    u16* __restrict__ xT) {           // [8][64][64][64] bf16 transposed
  __shared__ float tile[64][65];
  int bid = blockIdx.x;               // grid 512
  int t = threadIdx.x;
  int tid = bid * 256 + t;

  if (tid < 4608) {
    int nt = tid / 1152, ks = (tid / 64) % 18, lane = tid & 63;
    int co = nt * 16 + (lane & 15);
    int n = ks >> 1, s = ks & 1;
    int cl8 = (lane >> 4) << 3;
    u16* dst = wfrag + tid * 8;
    #pragma unroll
    for (int j = 0; j < 8; ++j) {
      int c = s * 32 + cl8 + j;
      dst[j] = f2bf(wconv[co * 576 + c * 9 + n]);
    }
  }
  if (tid >= 8192 && tid < 10496) {
    int idx = tid - 8192;             // [0, 2304)
    int nt2 = idx / 1152, ks = (idx / 64) % 18, lane = idx & 63;
    int o = nt2 * 16 + (lane & 15);
    int n = ks >> 1, s = ks & 1;
    int cl8 = (lane >> 4) << 3;
    u16* dst = wofrag + idx * 8;
    #pragma unroll
    for (int j = 0; j < 8; ++j) {
      int c = s * 32 + cl8 + j;
      float v = (o < 18) ? woff[(o * 64 + c) * 9 + n] : 0.f;
      dst[j] = f2bf(v);
    }
  }

  // transpose one (b,h) row-plane: 64 c x 64 w f32 -> 64 w x 64 c bf16
  int bh = ((bid & 7) << 6) | (bid >> 3);   // XCD k -> batch k
  const float* xb = x + (bh >> 6) * 262144 + (bh & 63) * 64;
  int w = t & 63, cr = t >> 6;
  #pragma unroll
  for (int i = 0; i < 16; ++i) {
    int c = cr * 16 + i;
    tile[c][w] = xb[c * 4096 + w];          // coalesced read
  }
  __syncthreads();
  // write bf16 pairs: lane c2 covers c = {2*c2, 2*c2+1}; 32 lanes = 128B/w-row
  u32* dstT = (u32*)(xT + bh * 4096);       // u32 = 2 bf16
  int c2 = t & 31, wr = t >> 5;             // wr in [0,8)
  #pragma unroll
  for (int i = 0; i < 8; ++i) {
    int w2 = wr * 8 + i;
    u32 lo = f2bf(tile[c2 * 2][w2]);
    u32 hi = f2bf(tile[c2 * 2 + 1][w2]);
    dstT[w2 * 32 + c2] = lo | (hi << 16);   // coalesced, 2-way LDS free
  }
}

// ---------- k2: offset GEMM + sample + main GEMM, 1024 blocks x 256 ----------
// block = (b, h, wh): 32 w columns (2 subtiles of 16). LDS 39680B -> 4 blk/CU.
__global__ __launch_bounds__(256, 4) void k2_sample(
    const u16*  __restrict__ xT,        // [8][64][64][64] bf16 [h][w][c]
    const u16*  __restrict__ wfrag,     // main-conv B-fragments
    const u16*  __restrict__ wofrag,    // offset-conv B-fragments
    const float* __restrict__ boff,     // [18]
    float* __restrict__ out) {          // [8][64][64][64]
  __shared__ __align__(16) u16 xim[32 * XOS_STRIDE]; // 37376B main A-tile
  __shared__ float offs_lds[576];                    // 2304B [o(18)][wl(32)]

  int bid = blockIdx.x;
  int b = bid & 7;                 // XCD k -> batch k
  int r = bid >> 3;                // 0..127
  int h = r >> 1, wh = r & 1;      // wh: which 32-w half
  int t = threadIdx.x;
  int cg4 = t & 15;                // c = cg4*4
  int wls = t >> 4;                // 0..15 (w lane within a 16-subtile)
  const u16* xTb = xT + b * 262144;

  // ---- 1) offset GEMM: waves 0,1; A-fragments loaded DIRECTLY from xT ----
  {
    int wv = t >> 6;
    int lane = t & 63;
    if (wv < 2) {
      int wl  = (lane & 15) + 16 * wv;       // row within 32-w tile
      int w_g = wh * 32 + wl;
      int cb0 = (lane >> 4) << 3;            // c sub-base (0,8,16,24)
      const s8v* Wo = (const s8v*)wofrag;
      f4v a0 = {0.f, 0.f, 0.f, 0.f}, a1 = {0.f, 0.f, 0.f, 0.f};
      #pragma unroll
      for (int ks = 0; ks < 18; ++ks) {
        int n  = ks >> 1;
        int cb = ((ks & 1) << 5) + cb0;      // c = s*32 + cb0 .. +8
        int hh = h + (n / 3) - 1;
        int ww = w_g + (n % 3) - 1;
        s8v a = {0, 0, 0, 0, 0, 0, 0, 0};
        if (hh >= 0 && hh < 64 && ww >= 0 && ww < 64)
          a = *(const s8v*)(xTb + (hh * 64 + ww) * 64 + cb);   // 16B aligned
        a0 = __builtin_amdgcn_mfma_f32_16x16x32_bf16(a, Wo[ks * 64 + lane], a0, 0, 0, 0);
        a1 = __builtin_amdgcn_mfma_f32_16x16x32_bf16(a, Wo[(18 + ks) * 64 + lane], a1, 0, 0, 0);
      }
      // D: col = lane&15 -> o, row = quad*4+reg -> w-in-subtile
      int quad = lane >> 4, ol = lane & 15;
      float bo0 = boff[ol];
      #pragma unroll
      for (int r4 = 0; r4 < 4; ++r4)
        offs_lds[ol * 32 + wv * 16 + quad * 4 + r4] = a0[r4] + bo0;
      if (ol < 2) {
        float bo1 = boff[16 + ol];
        #pragma unroll
        for (int r4 = 0; r4 < 4; ++r4)
          offs_lds[(16 + ol) * 32 + wv * 16 + quad * 4 + r4] = a1[r4] + bo1;
      }
    }
  }
  __syncthreads();   // offsets ready

  // ---- 2) coords + bilinear gather -> write xim main A-tile ----
  #pragma unroll
  for (int it = 0; it < 2; ++it) {
    int wl = wls + 16 * it;
    int w_g = wh * 32 + wl;
    u32 qa[9];
    f4v gg[9];
    #pragma unroll
    for (int n = 0; n < 9; ++n) {
      float ox = offs_lds[n * 32 + wl];
      float oy = offs_lds[(9 + n) * 32 + wl];
      float px = (float)(h + (n / 3)) + ox;
      float py = (float)(w_g + (n % 3)) + oy;
      float fx = floorf(px), fy = floorf(py);
      float pxc  = fminf(fmaxf(px, 0.f), 65.f);
      float pyc  = fminf(fmaxf(py, 0.f), 65.f);
      float fltx = fminf(fmaxf(fx, 0.f), 65.f);
      float flty = fminf(fmaxf(fy, 0.f), 65.f);
      float frbx = fminf(fmaxf(fx + 1.f, 0.f), 65.f);
      float frby = fminf(fmaxf(fy + 1.f, 0.f), 65.f);
      float ax = 1.f + fltx - pxc, bx = 1.f - frbx + pxc;
      float ay = 1.f + flty - pyc, by = 1.f - frby + pyc;
      float glt = ax * ay, grb = bx * by, glb = ax * by, grt = bx * ay;

      int ilt = (int)fltx, jlt = (int)flty, irb = (int)frbx, jrb = (int)frby;
      bool bi0 = (ilt >= 1 && ilt <= 64), bj0 = (jlt >= 1 && jlt <= 64);
      bool bi1 = (irb >= 1 && irb <= 64), bj1 = (jrb >= 1 && jrb <= 64);
      u32 i0 = bi0 ? (u32)(ilt - 1) : 0u;
      u32 j0 = bj0 ? (u32)(jlt - 1) : 0u;
      u32 i1 = bi1 ? (u32)(irb - 1) : 0u;
      u32 j1 = bj1 ? (u32)(jrb - 1) : 0u;
      qa[n] = i0 | (j0 << 8) | (i1 << 16) | (j1 << 24);
      f4v gv;
      gv[0] = (bi0 && bj0) ? glt : 0.f;
      gv[1] = (bi1 && bj1) ? grb : 0.f;
      gv[2] = (bi0 && bj1) ? glb : 0.f;
      gv[3] = (bi1 && bj0) ? grt : 0.f;
      gg[n] = gv;
    }
    const u16* xq = xTb + cg4 * 4;
    u16* xrow = xim + wl * XOS_STRIDE + cg4 * 4;
    #pragma unroll
    for (int n = 0; n < 9; ++n) {
      u32 q = qa[n];
      f4v g = gg[n];
      int i0 = (int)(q & 255u) << 12;          // *4096 u16 (row stride 64*64)
      int j0 = (int)((q >> 8) & 255u) << 6;    // *64 u16
      int i1 = (int)((q >> 16) & 255u) << 12;
      int j1 = (int)(q >> 24) << 6;
      f4v lt = bf2f4(*(const s4v*)(xq + i0 + j0));
      f4v rb = bf2f4(*(const s4v*)(xq + i1 + j1));
      f4v lb = bf2f4(*(const s4v*)(xq + i0 + j1));
      f4v rt = bf2f4(*(const s4v*)(xq + i1 + j0));
      f4v v  = g[0] * lt + g[1] * rb + g[2] * lb + g[3] * rt;
      s4v pk;
      pk[0] = (short)f2bf(v[0]);
      pk[1] = (short)f2bf(v[1]);
      pk[2] = (short)f2bf(v[2]);
      pk[3] = (short)f2bf(v[3]);
      *(s4v*)(xrow + n * 64) = pk;             // k = n*64 + cg4*4
    }
  }
  __syncthreads();

  // ---- 3) main GEMM: wave wv owns co-tile wv; B loaded once, used twice ----
  {
    int wv = t >> 6;
    int lane = t & 63;
    int aoff0 = (lane & 15) * XOS_STRIDE + ((lane >> 4) << 3);
    int aoff1 = aoff0 + 16 * XOS_STRIDE;
    const s8v* Wf = (const s8v*)wfrag;
    f4v acc0 = {0.f, 0.f, 0.f, 0.f}, acc1 = {0.f, 0.f, 0.f, 0.f};
    #pragma unroll
    for (int ks = 0; ks < 18; ++ks) {
      s8v b0 = Wf[(wv * 18 + ks) * 64 + lane];
      s8v a0 = *(const s8v*)(xim + aoff0 + ks * 32);
      s8v a1 = *(const s8v*)(xim + aoff1 + ks * 32);
      acc0 = __builtin_amdgcn_mfma_f32_16x16x32_bf16(a0, b0, acc0, 0, 0, 0);
      acc1 = __builtin_amdgcn_mfma_f32_16x16x32_bf16(a1, b0, acc1, 0, 0, 0);
    }
    // store: D layout col=lane&15 (co), row=quad*4+r (w-local)
    int quad = lane >> 4;
    int co = wv * 16 + (lane & 15);
    float* ob = out + b * 262144 + co * 4096 + h * 64 + wh * 32;
    *(f4v*)(ob + quad * 4)      = acc0;
    *(f4v*)(ob + 16 + quad * 4) = acc1;
  }
}

extern "C" void kernel_launch(void* const* d_in, const int* in_sizes, int n_in,
                              void* d_out, int out_size, void* d_ws, size_t ws_size,
                              hipStream_t stream) {
  const float *x = nullptr, *woff = nullptr, *boff = nullptr, *wconv = nullptr;
  for (int i = 0; i < n_in; ++i) {
    switch (in_sizes[i]) {
      case 2097152: x     = (const float*)d_in[i]; break;
      case 10368:   woff  = (const float*)d_in[i]; break;
      case 18:      boff  = (const float*)d_in[i]; break;
      case 36864:   wconv = (const float*)d_in[i]; break;
      default: break;
    }
  }
  if (!x)     x     = (const float*)d_in[0];
  if (!woff)  woff  = (const float*)d_in[1];
  if (!boff)  boff  = (const float*)d_in[2];
  if (!wconv) wconv = (const float*)d_in[3];
  float* out = (float*)d_out;

  u16* wfrag  = (u16*)d_ws;                        // 73728 B
  u16* wofrag = (u16*)((char*)d_ws + 73728);       // 36864 B (ends 110592)
  u16* xT     = (u16*)((char*)d_ws + 131072);      // 4194304 B bf16 (ends 4325376)

  k01<<<512, 256, 0, stream>>>(x, wconv, woff, wfrag, wofrag, xT);
  k2_sample<<<1024, 256, 0, stream>>>(xT, wfrag, wofrag, boff, out);
}